// Round 6
// baseline (363.621 us; speedup 1.0000x reference)
//
#include <hip/hip_runtime.h>

#define NN 10000
#define NE 160000
#define NE2 (NE + NN)
#define NG 64
#define EDIM 32

typedef _Float16 f16;
typedef __attribute__((ext_vector_type(2))) _Float16 f16x2;
typedef __attribute__((ext_vector_type(4))) _Float16 f16x4;
typedef __attribute__((ext_vector_type(8))) _Float16 f16x8;
typedef __attribute__((ext_vector_type(4))) float f32x4;
typedef __attribute__((ext_vector_type(8))) unsigned short u16x8;

__device__ __forceinline__ float lrelu(float x) { return fmaxf(x, 0.2f * x); }
__device__ __forceinline__ float elu1(float x) { return x > 0.f ? x : __expf(x) - 1.f; }

// ========== weight prep body (unchanged from r5) ==========

template <int CIN, int C>
__device__ __forceinline__ void wprep_body(int b, int tid,
                                           const float* __restrict__ W,
                                           const float* __restrict__ We,
                                           const float* __restrict__ as_,
                                           const float* __restrict__ ad_,
                                           const float* __restrict__ ae_,
                                           f16* __restrict__ Bt,
                                           float* __restrict__ asd,
                                           float* __restrict__ Wf,
                                           float (*t)[33]) {
    constexpr int K4 = 4 * CIN;
    constexpr int KT = CIN / 32, CT = C / 32;
    constexpr int TB = 4 * KT * CT;
    constexpr int FB = CIN / 64;
    if (b < TB) {
        int h = b / (KT * CT);
        int rem = b % (KT * CT);
        int k0 = (rem / CT) * 32, c0 = (rem % CT) * 32;
        int i = tid >> 5, j = tid & 31;
#pragma unroll
        for (int it = 0; it < 4; ++it)
            t[i + it * 8][j] = W[(size_t)(k0 + i + it * 8) * (4 * C) + h * C + c0 + j];
        __syncthreads();
#pragma unroll
        for (int it = 0; it < 4; ++it) {
            int jj = (tid >> 5) + it * 8, ii = tid & 31;
            Bt[(size_t)(c0 + jj) * K4 + h * CIN + k0 + ii] = (f16)t[ii][jj];
        }
    } else if (b < TB + FB) {
        int k = (b - TB) * 64 + (tid >> 2), h = tid & 3;
        const float4* wr = (const float4*)(W + (size_t)k * (4 * C) + h * C);
        const float4* a4 = (const float4*)(as_ + h * C);
        const float4* d4 = (const float4*)(ad_ + h * C);
        float s = 0.f, d = 0.f;
        for (int c = 0; c < C / 4; ++c) {
            float4 w = wr[c], av = a4[c], dv = d4[c];
            s += w.x * av.x + w.y * av.y + w.z * av.z + w.w * av.w;
            d += w.x * dv.x + w.y * dv.y + w.z * dv.z + w.w * dv.w;
        }
        asd[h * CIN + k] = s;
        asd[4 * CIN + h * CIN + k] = d;
    } else if (tid < 128) {
        int dd = tid >> 2, h = tid & 3;
        const float4* wr = (const float4*)(We + (size_t)dd * (4 * C) + h * C);
        const float4* a4 = (const float4*)(ae_ + h * C);
        float s = 0.f;
        for (int c = 0; c < C / 4; ++c) {
            float4 w = wr[c], av = a4[c];
            s += w.x * av.x + w.y * av.y + w.z * av.z + w.w * av.w;
        }
        Wf[dd * 4 + h] = s;
    }
}

// ===== k_init: wprep(331 blocks) | deg atomics(625) | x cast(1250) | invc(1) =====

__global__ __launch_bounds__(256) void k_init(
    const float* W1, const float* We1, const float* as1, const float* ad1, const float* ae1,
    f16* Bt1, float* asd1, float* Wf1,
    const float* W2, const float* We2, const float* as2, const float* ad2, const float* ae2,
    f16* Bt2, float* asd2, float* Wf2,
    const float* W3, const float* We3, const float* as3, const float* ad3, const float* ae3,
    f16* Bt3, float* asd3, float* Wf3,
    const int* ei, int* deg, const float* x, f16* x16,
    const int* batch, float* invc) {
    __shared__ float t[32][33];
    int b = blockIdx.x, tid = threadIdx.x;
    if (b < 67) {
        wprep_body<128, 128>(b, tid, W1, We1, as1, ad1, ae1, Bt1, asd1, Wf1, t);
    } else if (b < 198) {
        wprep_body<128, 256>(b - 67, tid, W2, We2, as2, ad2, ae2, Bt2, asd2, Wf2, t);
    } else if (b < 331) {
        wprep_body<256, 128>(b - 198, tid, W3, We3, as3, ad3, ae3, Bt3, asd3, Wf3, t);
    } else if (b < 956) {
        int e = (b - 331) * 256 + tid;  // 625 blocks exact
        atomicAdd(&deg[ei[NE + e]], 1);
    } else if (b < 2206) {
        int i = (b - 956) * 256 + tid;  // 1250 blocks exact, per 4 elems
        float4 v = ((const float4*)x)[i];
        f16x4 o;
        o[0] = (f16)v.x; o[1] = (f16)v.y; o[2] = (f16)v.z; o[3] = (f16)v.w;
        *(f16x4*)(x16 + i * 4) = o;
    } else if (tid < NG) {
        int g = tid;
        int lo = 0, hi = NN;
        while (lo < hi) { int mid = (lo + hi) >> 1; if (batch[mid] < g) lo = mid + 1; else hi = mid; }
        int start = lo;
        lo = start; hi = NN;
        while (lo < hi) { int mid = (lo + hi) >> 1; if (batch[mid] < g + 1) lo = mid + 1; else hi = mid; }
        invc[g] = 1.f / fmaxf((float)(lo - start), 1.f);
    }
}

// ============== scan (row_ptr/cursor) ==============

__global__ __launch_bounds__(1024) void k_scan2(const int* __restrict__ deg,
                                                int* __restrict__ row_ptr,
                                                int* __restrict__ cursor) {
    int tid = threadIdx.x;
    int vals[10];
    int run = 0;
#pragma unroll
    for (int i = 0; i < 10; ++i) {
        int n = tid * 10 + i;
        int v = (n < NN) ? (deg[n] + 1) : 0;
        run += v;
        vals[i] = run;
    }
    int total = run;
    int lane = tid & 63, wid = tid >> 6;
    int sc = total;
#pragma unroll
    for (int off = 1; off < 64; off <<= 1) {
        int t = __shfl_up(sc, off);
        if (lane >= off) sc += t;
    }
    __shared__ int wsum[16];
    if (lane == 63) wsum[wid] = sc;
    __syncthreads();
    if (tid == 0) {
        int a = 0;
#pragma unroll
        for (int w = 0; w < 16; ++w) { int t = wsum[w]; wsum[w] = a; a += t; }
    }
    __syncthreads();
    int excl = sc - total + wsum[wid];
#pragma unroll
    for (int i = 0; i < 10; ++i) {
        int n = tid * 10 + i;
        if (n < NN) {
            int prev = i ? vals[i - 1] : 0;
            row_ptr[n + 1] = excl + vals[i];
            cursor[n] = excl + prev;
        }
    }
    if (tid == 0) row_ptr[0] = 0;
}

// ===== k_fill_e4: CSR fill + real-edge e4 (665 blocks) | layer-1 alnode (2500) =====

__global__ __launch_bounds__(256) void k_fill_e4(const int* __restrict__ ei,
                                                 int* __restrict__ cursor,
                                                 int* __restrict__ src_sorted,
                                                 int* __restrict__ selfpos,
                                                 const float* __restrict__ eattr,
                                                 const float* __restrict__ Wf1,
                                                 const float* __restrict__ Wf2,
                                                 const float* __restrict__ Wf3,
                                                 float* __restrict__ e4all,
                                                 const f16* __restrict__ x16,
                                                 const float* __restrict__ asd1,
                                                 float* __restrict__ als1,
                                                 float* __restrict__ ald1) {
    __shared__ float smem[1024];
    int b = blockIdx.x, tid = threadIdx.x;
    if (b < 665) {
        for (int i = tid; i < 384; i += 256)
            smem[i] = (i < 128) ? Wf1[i] : (i < 256) ? Wf2[i - 128] : Wf3[i - 256];
        __syncthreads();
        int e = b * 256 + tid;
        if (e >= NE2) return;
        if (e < NE) {
            int s = ei[e], d = ei[NE + e];
            int p = atomicAdd(&cursor[d], 1);
            src_sorted[p] = s;
            float4 v[8];
            const float4* er = (const float4*)(eattr + (size_t)e * EDIM);
#pragma unroll
            for (int i = 0; i < 8; ++i) v[i] = er[i];
#pragma unroll
            for (int l = 0; l < 3; ++l) {
                float a0 = 0.f, a1 = 0.f, a2 = 0.f, a3 = 0.f;
#pragma unroll
                for (int d4 = 0; d4 < 8; ++d4) {
                    const float* w = &smem[l * 128 + d4 * 16];
                    a0 += v[d4].x * w[0] + v[d4].y * w[4] + v[d4].z * w[8]  + v[d4].w * w[12];
                    a1 += v[d4].x * w[1] + v[d4].y * w[5] + v[d4].z * w[9]  + v[d4].w * w[13];
                    a2 += v[d4].x * w[2] + v[d4].y * w[6] + v[d4].z * w[10] + v[d4].w * w[14];
                    a3 += v[d4].x * w[3] + v[d4].y * w[7] + v[d4].z * w[11] + v[d4].w * w[15];
                }
                ((float4*)e4all)[(size_t)l * NE2 + p] = make_float4(a0, a1, a2, a3);
            }
        } else {
            int n = e - NE;
            int p = atomicAdd(&cursor[n], 1);
            src_sorted[p] = n;
            selfpos[n] = p;
        }
    } else {
        // layer-1 alnode: als1[n,h] = x16[n]·âs1[h]
        float* sA = smem;
        float* sD = smem + 512;
        for (int i = tid; i < 512; i += 256) { sA[i] = asd1[i]; sD[i] = asd1[512 + i]; }
        __syncthreads();
        int wid = tid >> 6, lane = tid & 63;
        int node = (b - 665) * 4 + wid;
        int h = lane >> 4, c16 = lane & 15;
        const f16* xr = x16 + (size_t)node * 128 + c16 * 8;
        f16x8 v = *(const f16x8*)xr;
        float s = 0.f, d = 0.f;
#pragma unroll
        for (int i = 0; i < 8; ++i) {
            float f = (float)v[i];
            s += f * sA[h * 128 + c16 * 8 + i];
            d += f * sD[h * 128 + c16 * 8 + i];
        }
#pragma unroll
        for (int off = 1; off < 16; off <<= 1) { s += __shfl_xor(s, off); d += __shfl_xor(d, off); }
        if (c16 == 0) { als1[node * 4 + h] = s; ald1[node * 4 + h] = d; }
    }
}

// ===== self-loop e4 = mean of real-edge e4 (linearity of scatter-mean) =====

__global__ __launch_bounds__(256) void k_e4self(const int* __restrict__ row_ptr,
                                                const int* __restrict__ selfpos,
                                                float* __restrict__ e4all) {
    int t = blockIdx.x * 256 + threadIdx.x;  // 625 blocks exact: NN*16 threads
    int node = t >> 4, sub = t & 15;
    if (sub >= 12) return;
    int l = sub >> 2, c = sub & 3;
    int beg = row_ptr[node], end = row_ptr[node + 1];
    int sp = selfpos[node];
    const float* base = e4all + (size_t)l * NE2 * 4 + c;
    float s = 0.f;
    for (int j = beg; j < end; ++j)
        if (j != sp) s += base[(size_t)j * 4];
    float inv = 1.f / fmaxf((float)(end - beg - 1), 1.f);
    e4all[(size_t)l * NE2 * 4 + (size_t)sp * 4 + c] = s * inv;
}

// ===== fused logits + softmax + input-feature aggregation (unchanged) =====

template <int CIN>
__global__ __launch_bounds__(256) void k_agg2(const int* __restrict__ row_ptr,
                                              const int* __restrict__ src_sorted,
                                              const float* __restrict__ e4,
                                              const float* __restrict__ als,
                                              const float* __restrict__ ald,
                                              const f16* __restrict__ xp,
                                              f16* __restrict__ aggcat) {
    constexpr int EPL = CIN / 64;
    int wid = threadIdx.x >> 6, lane = threadIdx.x & 63;
    int node = blockIdx.x * 4 + wid;
    int beg = row_ptr[node], end = row_ptr[node + 1];
    float4 ad4 = ((const float4*)ald)[node];
    const float4* e44 = (const float4*)e4;
    const float4* als4 = (const float4*)als;
    float s0 = 0.f, s1 = 0.f, s2 = 0.f, s3 = 0.f;
    float a0[EPL] = {}, a1[EPL] = {}, a2[EPL] = {}, a3[EPL] = {};
    const f16* xbase = xp + lane * EPL;
#pragma unroll 4
    for (int j = beg; j < end; ++j) {
        int src = src_sorted[j];
        float4 ev = e44[j];
        float4 av = als4[src];
        float e0 = __expf(lrelu(ev.x + av.x + ad4.x));
        float e1 = __expf(lrelu(ev.y + av.y + ad4.y));
        float e2 = __expf(lrelu(ev.z + av.z + ad4.z));
        float e3 = __expf(lrelu(ev.w + av.w + ad4.w));
        s0 += e0; s1 += e1; s2 += e2; s3 += e3;
        const f16* xr = xbase + (size_t)src * CIN;
        if (EPL == 2) {
            f16x2 v = *(const f16x2*)xr;
            float f0 = (float)v[0], f1 = (float)v[1];
            a0[0] += e0 * f0; a0[1] += e0 * f1;
            a1[0] += e1 * f0; a1[1] += e1 * f1;
            a2[0] += e2 * f0; a2[1] += e2 * f1;
            a3[0] += e3 * f0; a3[1] += e3 * f1;
        } else {
            f16x4 v = *(const f16x4*)xr;
#pragma unroll
            for (int i = 0; i < 4; ++i) {
                float f = (float)v[i];
                a0[i] += e0 * f; a1[i] += e1 * f; a2[i] += e2 * f; a3[i] += e3 * f;
            }
        }
    }
    float i0 = 1.f / (s0 + 1e-16f), i1 = 1.f / (s1 + 1e-16f);
    float i2 = 1.f / (s2 + 1e-16f), i3 = 1.f / (s3 + 1e-16f);
    f16* ob = aggcat + (size_t)node * 4 * CIN + lane * EPL;
    if (EPL == 2) {
        f16x2 o;
        o[0] = (f16)(a0[0] * i0); o[1] = (f16)(a0[1] * i0); *(f16x2*)(ob + 0 * CIN) = o;
        o[0] = (f16)(a1[0] * i1); o[1] = (f16)(a1[1] * i1); *(f16x2*)(ob + 1 * CIN) = o;
        o[0] = (f16)(a2[0] * i2); o[1] = (f16)(a2[1] * i2); *(f16x2*)(ob + 2 * CIN) = o;
        o[0] = (f16)(a3[0] * i3); o[1] = (f16)(a3[1] * i3); *(f16x2*)(ob + 3 * CIN) = o;
    } else {
        f16x4 o;
#pragma unroll
        for (int i = 0; i < 4; ++i) o[i] = (f16)(a0[i] * i0);
        *(f16x4*)(ob + 0 * CIN) = o;
#pragma unroll
        for (int i = 0; i < 4; ++i) o[i] = (f16)(a1[i] * i1);
        *(f16x4*)(ob + 1 * CIN) = o;
#pragma unroll
        for (int i = 0; i < 4; ++i) o[i] = (f16)(a2[i] * i2);
        *(f16x4*)(ob + 2 * CIN) = o;
#pragma unroll
        for (int i = 0; i < 4; ++i) o[i] = (f16)(a3[i] * i3);
        *(f16x4*)(ob + 3 * CIN) = o;
    }
}

// ===== MFMA GEMM + elu/bias epilogue; optional fused next-layer als/ald =====
// als_n/ald_n must be pre-zeroed (atomicAdd partials across bn blocks).

template <int K4, int C, bool FUSE>
__global__ __launch_bounds__(256) void k_gemm_ep(const f16* __restrict__ A,
                                                 const f16* __restrict__ Bt,
                                                 const float* __restrict__ bias,
                                                 f16* __restrict__ hout,
                                                 const float* __restrict__ asd_n,
                                                 float* __restrict__ als_n,
                                                 float* __restrict__ ald_n) {
    __shared__ f16 Als[64 * 40];
    __shared__ f16 Bls[64 * 40];
    int bm = blockIdx.x * 64, bn = blockIdx.y * 64;
    int tid = threadIdx.x;
    int wid = tid >> 6, lane = tid & 63;
    int wrow = (wid >> 1) * 32, wcol = (wid & 1) * 32;
    int fr = lane & 15, fk = (lane >> 4) * 8;
    f32x4 acc[2][2];
#pragma unroll
    for (int m = 0; m < 2; ++m)
#pragma unroll
        for (int n = 0; n < 2; ++n) acc[m][n] = (f32x4){0.f, 0.f, 0.f, 0.f};

    int srow = tid >> 2, spart = tid & 3;
    for (int k0 = 0; k0 < K4; k0 += 32) {
        int gr = bm + srow;
        u16x8 va = (u16x8)0;
        if (gr < NN) va = *(const u16x8*)(A + (size_t)gr * K4 + k0 + spart * 8);
        *(u16x8*)&Als[srow * 40 + spart * 8] = va;
        u16x8 vb = *(const u16x8*)(Bt + (size_t)(bn + srow) * K4 + k0 + spart * 8);
        *(u16x8*)&Bls[srow * 40 + spart * 8] = vb;
        __syncthreads();
        f16x8 af[2], bf[2];
        af[0] = *(const f16x8*)&Als[(wrow + fr) * 40 + fk];
        af[1] = *(const f16x8*)&Als[(wrow + 16 + fr) * 40 + fk];
        bf[0] = *(const f16x8*)&Bls[(wcol + fr) * 40 + fk];
        bf[1] = *(const f16x8*)&Bls[(wcol + 16 + fr) * 40 + fk];
#pragma unroll
        for (int m = 0; m < 2; ++m)
#pragma unroll
            for (int n = 0; n < 2; ++n)
                acc[m][n] = __builtin_amdgcn_mfma_f32_16x16x32_f16(af[m], bf[n], acc[m][n], 0, 0, 0);
        __syncthreads();
    }

    int cr = (lane >> 4) * 4, cc = lane & 15;
    int col0 = bn + wcol + cc, col1 = col0 + 16;
    float b0 = bias[col0], b1 = bias[col1];
    float wa0[4], wa1[4], wd0[4], wd1[4];
    if (FUSE) {
#pragma unroll
        for (int h = 0; h < 4; ++h) {
            wa0[h] = asd_n[h * C + col0];
            wa1[h] = asd_n[h * C + col1];
            wd0[h] = asd_n[4 * C + h * C + col0];
            wd1[h] = asd_n[4 * C + h * C + col1];
        }
    }
#pragma unroll
    for (int m = 0; m < 2; ++m) {
#pragma unroll
        for (int r = 0; r < 4; ++r) {
            int row = bm + wrow + m * 16 + cr + r;
            if (row >= NN) continue;   // uniform within 16-lane shuffle group
            float v0 = elu1(0.25f * acc[m][0][r] + b0);
            float v1 = elu1(0.25f * acc[m][1][r] + b1);
            f16* cp = hout + (size_t)row * C + col0;
            cp[0]  = (f16)v0;
            cp[16] = (f16)v1;
            if (FUSE) {
                float s[4], d[4];
#pragma unroll
                for (int h = 0; h < 4; ++h) {
                    s[h] = v0 * wa0[h] + v1 * wa1[h];
                    d[h] = v0 * wd0[h] + v1 * wd1[h];
                }
#pragma unroll
                for (int off = 1; off < 16; off <<= 1) {
#pragma unroll
                    for (int h = 0; h < 4; ++h) {
                        s[h] += __shfl_xor(s[h], off);
                        d[h] += __shfl_xor(d[h], off);
                    }
                }
                if (cc == 0) {
#pragma unroll
                    for (int h = 0; h < 4; ++h) {
                        atomicAdd(&als_n[row * 4 + h], s[h]);
                        atomicAdd(&ald_n[row * 4 + h], d[h]);
                    }
                }
            }
        }
    }
}

// ===== layer-3 GEMM with fused mean-pool epilogue =====

template <int K4, int C>
__global__ __launch_bounds__(256) void k_gemm_pool(const f16* __restrict__ A,
                                                   const f16* __restrict__ Bt,
                                                   const float* __restrict__ bias,
                                                   const int* __restrict__ batch,
                                                   const float* __restrict__ invc,
                                                   float* __restrict__ out) {
    __shared__ f16 Als[64 * 40];
    __shared__ f16 Bls[64 * 40];
    int bm = blockIdx.x * 64, bn = blockIdx.y * 64;
    int tid = threadIdx.x;
    int wid = tid >> 6, lane = tid & 63;
    int wrow = (wid >> 1) * 32, wcol = (wid & 1) * 32;
    int fr = lane & 15, fk = (lane >> 4) * 8;
    f32x4 acc[2][2];
#pragma unroll
    for (int m = 0; m < 2; ++m)
#pragma unroll
        for (int n = 0; n < 2; ++n) acc[m][n] = (f32x4){0.f, 0.f, 0.f, 0.f};

    int srow = tid >> 2, spart = tid & 3;
    for (int k0 = 0; k0 < K4; k0 += 32) {
        int gr = bm + srow;
        u16x8 va = (u16x8)0;
        if (gr < NN) va = *(const u16x8*)(A + (size_t)gr * K4 + k0 + spart * 8);
        *(u16x8*)&Als[srow * 40 + spart * 8] = va;
        u16x8 vb = *(const u16x8*)(Bt + (size_t)(bn + srow) * K4 + k0 + spart * 8);
        *(u16x8*)&Bls[srow * 40 + spart * 8] = vb;
        __syncthreads();
        f16x8 af[2], bf[2];
        af[0] = *(const f16x8*)&Als[(wrow + fr) * 40 + fk];
        af[1] = *(const f16x8*)&Als[(wrow + 16 + fr) * 40 + fk];
        bf[0] = *(const f16x8*)&Bls[(wcol + fr) * 40 + fk];
        bf[1] = *(const f16x8*)&Bls[(wcol + 16 + fr) * 40 + fk];
#pragma unroll
        for (int m = 0; m < 2; ++m)
#pragma unroll
            for (int n = 0; n < 2; ++n)
                acc[m][n] = __builtin_amdgcn_mfma_f32_16x16x32_f16(af[m], bf[n], acc[m][n], 0, 0, 0);
        __syncthreads();
    }

    int cr = (lane >> 4) * 4, cc = lane & 15;
    float b0 = bias[bn + wcol + cc], b1 = bias[bn + wcol + 16 + cc];
#pragma unroll
    for (int m = 0; m < 2; ++m) {
#pragma unroll
        for (int r = 0; r < 4; ++r) {
            int row = bm + wrow + m * 16 + cr + r;
            if (row >= NN) continue;
            int g = batch[row];
            float ic = invc[g];
            float* op = out + (size_t)g * C + bn + wcol + cc;
            atomicAdd(op,      elu1(0.25f * acc[m][0][r] + b0) * ic);
            atomicAdd(op + 16, elu1(0.25f * acc[m][1][r] + b1) * ic);
        }
    }
}

// ============================ host side ============================

struct Ws {
    f16 *x16, *hA, *hB, *aggcat, *Wt1, *Wt2, *Wt3;
    float *als1, *ald1;
    int *deg;                                    // zero-group start
    float *als2, *ald2, *als3, *ald3;            // zero-group (contiguous after deg)
    float *e4all, *asd1, *asd2, *asd3, *Wf1, *Wf2, *Wf3, *invc;
    int *row_ptr, *cursor, *src_sorted, *selfpos;
};

static void carve(void* base, Ws& w) {
    char* p = (char*)base;
    size_t off = 0;
    auto take = [&](size_t bytes) {
        off = (off + 255) & ~(size_t)255;
        void* r = p + off;
        off += bytes;
        return r;
    };
    w.x16        = (f16*)take((size_t)NN * 128 * 2);
    w.hA         = (f16*)take((size_t)NN * 128 * 2);
    w.hB         = (f16*)take((size_t)NN * 256 * 2);
    w.aggcat     = (f16*)take((size_t)NN * 1024 * 2);
    w.Wt1        = (f16*)take((size_t)512 * 128 * 2);
    w.Wt2        = (f16*)take((size_t)512 * 256 * 2);
    w.Wt3        = (f16*)take((size_t)1024 * 128 * 2);
    w.als1       = (float*)take((size_t)NN * 4 * 4);
    w.ald1       = (float*)take((size_t)NN * 4 * 4);
    // ---- zero group: deg + als2/ald2/als3/ald3 (one memset spans these) ----
    w.deg        = (int*)take((size_t)NN * 4);
    w.als2       = (float*)take((size_t)NN * 4 * 4);
    w.ald2       = (float*)take((size_t)NN * 4 * 4);
    w.als3       = (float*)take((size_t)NN * 4 * 4);
    w.ald3       = (float*)take((size_t)NN * 4 * 4);
    // ------------------------------------------------------------------------
    w.e4all      = (float*)take((size_t)3 * NE2 * 4 * 4);
    w.asd1       = (float*)take(2 * 4 * 128 * 4);
    w.asd2       = (float*)take(2 * 4 * 128 * 4);
    w.asd3       = (float*)take(2 * 4 * 256 * 4);
    w.Wf1        = (float*)take(128 * 4);
    w.Wf2        = (float*)take(128 * 4);
    w.Wf3        = (float*)take(128 * 4);
    w.invc       = (float*)take(NG * 4);
    w.row_ptr    = (int*)take((size_t)(NN + 1) * 4);
    w.cursor     = (int*)take((size_t)NN * 4);
    w.src_sorted = (int*)take((size_t)NE2 * 4);
    w.selfpos    = (int*)take((size_t)NN * 4);
}

extern "C" void kernel_launch(void* const* d_in, const int* in_sizes, int n_in,
                              void* d_out, int out_size, void* d_ws, size_t ws_size,
                              hipStream_t stream) {
    const float* x     = (const float*)d_in[0];
    const int*   ei    = (const int*)d_in[1];
    const float* eattr = (const float*)d_in[2];
    const int*   batch = (const int*)d_in[3];
    const float* W[3]  = {(const float*)d_in[4],  (const float*)d_in[10], (const float*)d_in[16]};
    const float* We[3] = {(const float*)d_in[5],  (const float*)d_in[11], (const float*)d_in[17]};
    const float* as_[3]= {(const float*)d_in[6],  (const float*)d_in[12], (const float*)d_in[18]};
    const float* ad_[3]= {(const float*)d_in[7],  (const float*)d_in[13], (const float*)d_in[19]};
    const float* ae_[3]= {(const float*)d_in[8],  (const float*)d_in[14], (const float*)d_in[20]};
    const float* b_[3] = {(const float*)d_in[9],  (const float*)d_in[15], (const float*)d_in[21]};
    float* out = (float*)d_out;

    Ws w;
    carve(d_ws, w);

    size_t zspan = (size_t)((char*)w.ald3 - (char*)w.deg) + (size_t)NN * 4 * 4;
    hipMemsetAsync(w.deg, 0, zspan, stream);
    hipMemsetAsync(out, 0, (size_t)NG * 128 * 4, stream);

    // ---- init: weight prep + deg + x cast + group inv-counts (1 launch) ----
    k_init<<<2207, 256, 0, stream>>>(
        W[0], We[0], as_[0], ad_[0], ae_[0], w.Wt1, w.asd1, w.Wf1,
        W[1], We[1], as_[1], ad_[1], ae_[1], w.Wt2, w.asd2, w.Wf2,
        W[2], We[2], as_[2], ad_[2], ae_[2], w.Wt3, w.asd3, w.Wf3,
        ei, w.deg, x, w.x16, batch, w.invc);

    k_scan2<<<1, 1024, 0, stream>>>(w.deg, w.row_ptr, w.cursor);

    // ---- CSR fill + real-edge e4 + layer-1 alnode (1 launch) ----
    k_fill_e4<<<3165, 256, 0, stream>>>(ei, w.cursor, w.src_sorted, w.selfpos, eattr,
                                        w.Wf1, w.Wf2, w.Wf3, w.e4all,
                                        w.x16, w.asd1, w.als1, w.ald1);
    k_e4self<<<625, 256, 0, stream>>>(w.row_ptr, w.selfpos, w.e4all);

    const float* e4_1 = w.e4all;
    const float* e4_2 = w.e4all + (size_t)NE2 * 4;
    const float* e4_3 = w.e4all + (size_t)2 * NE2 * 4;

    // ---- layer 1 ----
    k_agg2<128><<<NN / 4, 256, 0, stream>>>(w.row_ptr, w.src_sorted, e4_1, w.als1, w.ald1,
                                            w.x16, w.aggcat);
    k_gemm_ep<512, 128, true><<<dim3(157, 2), 256, 0, stream>>>(w.aggcat, w.Wt1, b_[0],
                                                                w.hA, w.asd2, w.als2, w.ald2);
    // ---- layer 2 ----
    k_agg2<128><<<NN / 4, 256, 0, stream>>>(w.row_ptr, w.src_sorted, e4_2, w.als2, w.ald2,
                                            w.hA, w.aggcat);
    k_gemm_ep<512, 256, true><<<dim3(157, 4), 256, 0, stream>>>(w.aggcat, w.Wt2, b_[1],
                                                                w.hB, w.asd3, w.als3, w.ald3);
    // ---- layer 3 + fused mean-pool ----
    k_agg2<256><<<NN / 4, 256, 0, stream>>>(w.row_ptr, w.src_sorted, e4_3, w.als3, w.ald3,
                                            w.hB, w.aggcat);
    k_gemm_pool<1024, 128><<<dim3(157, 2), 256, 0, stream>>>(w.aggcat, w.Wt3, b_[2],
                                                             batch, w.invc, out);
}

// Round 8
// 318.430 us; speedup vs baseline: 1.1419x; 1.1419x over previous
//
#include <hip/hip_runtime.h>

#define NN 10000
#define NE 160000
#define NE2 (NE + NN)
#define NG 64
#define EDIM 32

typedef _Float16 f16;
typedef __attribute__((ext_vector_type(2))) _Float16 f16x2;
typedef __attribute__((ext_vector_type(4))) _Float16 f16x4;
typedef __attribute__((ext_vector_type(8))) _Float16 f16x8;
typedef __attribute__((ext_vector_type(4))) float f32x4;
typedef __attribute__((ext_vector_type(8))) unsigned short u16x8;

__device__ __forceinline__ float lrelu(float x) { return fmaxf(x, 0.2f * x); }
__device__ __forceinline__ float elu1(float x) { return x > 0.f ? x : __expf(x) - 1.f; }

// ========== weight prep body ==========

template <int CIN, int C>
__device__ __forceinline__ void wprep_body(int b, int tid,
                                           const float* __restrict__ W,
                                           const float* __restrict__ We,
                                           const float* __restrict__ as_,
                                           const float* __restrict__ ad_,
                                           const float* __restrict__ ae_,
                                           f16* __restrict__ Bt,
                                           float* __restrict__ asd,
                                           float* __restrict__ Wf,
                                           float (*t)[33]) {
    constexpr int K4 = 4 * CIN;
    constexpr int KT = CIN / 32, CT = C / 32;
    constexpr int TB = 4 * KT * CT;
    constexpr int FB = CIN / 64;
    if (b < TB) {
        int h = b / (KT * CT);
        int rem = b % (KT * CT);
        int k0 = (rem / CT) * 32, c0 = (rem % CT) * 32;
        int i = tid >> 5, j = tid & 31;
#pragma unroll
        for (int it = 0; it < 4; ++it)
            t[i + it * 8][j] = W[(size_t)(k0 + i + it * 8) * (4 * C) + h * C + c0 + j];
        __syncthreads();
#pragma unroll
        for (int it = 0; it < 4; ++it) {
            int jj = (tid >> 5) + it * 8, ii = tid & 31;
            Bt[(size_t)(c0 + jj) * K4 + h * CIN + k0 + ii] = (f16)t[ii][jj];
        }
    } else if (b < TB + FB) {
        int k = (b - TB) * 64 + (tid >> 2), h = tid & 3;
        const float4* wr = (const float4*)(W + (size_t)k * (4 * C) + h * C);
        const float4* a4 = (const float4*)(as_ + h * C);
        const float4* d4 = (const float4*)(ad_ + h * C);
        float s = 0.f, d = 0.f;
        for (int c = 0; c < C / 4; ++c) {
            float4 w = wr[c], av = a4[c], dv = d4[c];
            s += w.x * av.x + w.y * av.y + w.z * av.z + w.w * av.w;
            d += w.x * dv.x + w.y * dv.y + w.z * dv.z + w.w * dv.w;
        }
        asd[h * CIN + k] = s;
        asd[4 * CIN + h * CIN + k] = d;
    } else if (tid < 128) {
        int dd = tid >> 2, h = tid & 3;
        const float4* wr = (const float4*)(We + (size_t)dd * (4 * C) + h * C);
        const float4* a4 = (const float4*)(ae_ + h * C);
        float s = 0.f;
        for (int c = 0; c < C / 4; ++c) {
            float4 w = wr[c], av = a4[c];
            s += w.x * av.x + w.y * av.y + w.z * av.z + w.w * av.w;
        }
        Wf[dd * 4 + h] = s;
    }
}

// ===== k_init: wprep(331) | deg atomics(625) | x cast(1250) | invc(1) =====

__global__ __launch_bounds__(256) void k_init(
    const float* W1, const float* We1, const float* as1, const float* ad1, const float* ae1,
    f16* Bt1, float* asd1, float* Wf1,
    const float* W2, const float* We2, const float* as2, const float* ad2, const float* ae2,
    f16* Bt2, float* asd2, float* Wf2,
    const float* W3, const float* We3, const float* as3, const float* ad3, const float* ae3,
    f16* Bt3, float* asd3, float* Wf3,
    const int* ei, int* deg, const float* x, f16* x16,
    const int* batch, float* invc) {
    __shared__ float t[32][33];
    int b = blockIdx.x, tid = threadIdx.x;
    if (b < 67) {
        wprep_body<128, 128>(b, tid, W1, We1, as1, ad1, ae1, Bt1, asd1, Wf1, t);
    } else if (b < 198) {
        wprep_body<128, 256>(b - 67, tid, W2, We2, as2, ad2, ae2, Bt2, asd2, Wf2, t);
    } else if (b < 331) {
        wprep_body<256, 128>(b - 198, tid, W3, We3, as3, ad3, ae3, Bt3, asd3, Wf3, t);
    } else if (b < 956) {
        int e = (b - 331) * 256 + tid;
        atomicAdd(&deg[ei[NE + e]], 1);
    } else if (b < 2206) {
        int i = (b - 956) * 256 + tid;
        float4 v = ((const float4*)x)[i];
        f16x4 o;
        o[0] = (f16)v.x; o[1] = (f16)v.y; o[2] = (f16)v.z; o[3] = (f16)v.w;
        *(f16x4*)(x16 + i * 4) = o;
    } else if (tid < NG) {
        int g = tid;
        int lo = 0, hi = NN;
        while (lo < hi) { int mid = (lo + hi) >> 1; if (batch[mid] < g) lo = mid + 1; else hi = mid; }
        int start = lo;
        lo = start; hi = NN;
        while (lo < hi) { int mid = (lo + hi) >> 1; if (batch[mid] < g + 1) lo = mid + 1; else hi = mid; }
        invc[g] = 1.f / fmaxf((float)(lo - start), 1.f);
    }
}

// ============== scan (row_ptr/cursor) ==============

__global__ __launch_bounds__(1024) void k_scan2(const int* __restrict__ deg,
                                                int* __restrict__ row_ptr,
                                                int* __restrict__ cursor) {
    int tid = threadIdx.x;
    int vals[10];
    int run = 0;
#pragma unroll
    for (int i = 0; i < 10; ++i) {
        int n = tid * 10 + i;
        int v = (n < NN) ? (deg[n] + 1) : 0;
        run += v;
        vals[i] = run;
    }
    int total = run;
    int lane = tid & 63, wid = tid >> 6;
    int sc = total;
#pragma unroll
    for (int off = 1; off < 64; off <<= 1) {
        int t = __shfl_up(sc, off);
        if (lane >= off) sc += t;
    }
    __shared__ int wsum[16];
    if (lane == 63) wsum[wid] = sc;
    __syncthreads();
    if (tid == 0) {
        int a = 0;
#pragma unroll
        for (int w = 0; w < 16; ++w) { int t = wsum[w]; wsum[w] = a; a += t; }
    }
    __syncthreads();
    int excl = sc - total + wsum[wid];
#pragma unroll
    for (int i = 0; i < 10; ++i) {
        int n = tid * 10 + i;
        if (n < NN) {
            int prev = i ? vals[i - 1] : 0;
            row_ptr[n + 1] = excl + vals[i];
            cursor[n] = excl + prev;
        }
    }
    if (tid == 0) row_ptr[0] = 0;
}

// ===== k_fill_e4: CSR fill + real-edge e4 (665 blocks) | layer-1 alnode (2500) =====

__global__ __launch_bounds__(256) void k_fill_e4(const int* __restrict__ ei,
                                                 int* __restrict__ cursor,
                                                 int* __restrict__ src_sorted,
                                                 int* __restrict__ selfpos,
                                                 const float* __restrict__ eattr,
                                                 const float* __restrict__ Wf1,
                                                 const float* __restrict__ Wf2,
                                                 const float* __restrict__ Wf3,
                                                 float* __restrict__ e4all,
                                                 const f16* __restrict__ x16,
                                                 const float* __restrict__ asd1,
                                                 float* __restrict__ als1,
                                                 float* __restrict__ ald1) {
    __shared__ float smem[1024];
    int b = blockIdx.x, tid = threadIdx.x;
    if (b < 665) {
        for (int i = tid; i < 384; i += 256)
            smem[i] = (i < 128) ? Wf1[i] : (i < 256) ? Wf2[i - 128] : Wf3[i - 256];
        __syncthreads();
        int e = b * 256 + tid;
        if (e >= NE2) return;
        if (e < NE) {
            int s = ei[e], d = ei[NE + e];
            int p = atomicAdd(&cursor[d], 1);
            src_sorted[p] = s;
            float4 v[8];
            const float4* er = (const float4*)(eattr + (size_t)e * EDIM);
#pragma unroll
            for (int i = 0; i < 8; ++i) v[i] = er[i];
#pragma unroll
            for (int l = 0; l < 3; ++l) {
                float a0 = 0.f, a1 = 0.f, a2 = 0.f, a3 = 0.f;
#pragma unroll
                for (int d4 = 0; d4 < 8; ++d4) {
                    const float* w = &smem[l * 128 + d4 * 16];
                    a0 += v[d4].x * w[0] + v[d4].y * w[4] + v[d4].z * w[8]  + v[d4].w * w[12];
                    a1 += v[d4].x * w[1] + v[d4].y * w[5] + v[d4].z * w[9]  + v[d4].w * w[13];
                    a2 += v[d4].x * w[2] + v[d4].y * w[6] + v[d4].z * w[10] + v[d4].w * w[14];
                    a3 += v[d4].x * w[3] + v[d4].y * w[7] + v[d4].z * w[11] + v[d4].w * w[15];
                }
                ((float4*)e4all)[(size_t)l * NE2 + p] = make_float4(a0, a1, a2, a3);
            }
        } else {
            int n = e - NE;
            int p = atomicAdd(&cursor[n], 1);
            src_sorted[p] = n;
            selfpos[n] = p;
        }
    } else {
        float* sA = smem;
        float* sD = smem + 512;
        for (int i = tid; i < 512; i += 256) { sA[i] = asd1[i]; sD[i] = asd1[512 + i]; }
        __syncthreads();
        int wid = tid >> 6, lane = tid & 63;
        int node = (b - 665) * 4 + wid;
        int h = lane >> 4, c16 = lane & 15;
        const f16* xr = x16 + (size_t)node * 128 + c16 * 8;
        f16x8 v = *(const f16x8*)xr;
        float s = 0.f, d = 0.f;
#pragma unroll
        for (int i = 0; i < 8; ++i) {
            float f = (float)v[i];
            s += f * sA[h * 128 + c16 * 8 + i];
            d += f * sD[h * 128 + c16 * 8 + i];
        }
#pragma unroll
        for (int off = 1; off < 16; off <<= 1) { s += __shfl_xor(s, off); d += __shfl_xor(d, off); }
        if (c16 == 0) { als1[node * 4 + h] = s; ald1[node * 4 + h] = d; }
    }
}

// ===== alnode: als[n,h] = h[n]·âs[h] (layers 2/3) =====

template <int CIN>
__global__ __launch_bounds__(256) void k_alnode2(const f16* __restrict__ xp,
                                                 const float* __restrict__ asd,
                                                 float* __restrict__ als,
                                                 float* __restrict__ ald) {
    __shared__ float sA[4 * CIN], sD[4 * CIN];
    for (int i = threadIdx.x; i < 4 * CIN; i += 256) { sA[i] = asd[i]; sD[i] = asd[4 * CIN + i]; }
    __syncthreads();
    int wid = threadIdx.x >> 6, lane = threadIdx.x & 63;
    int node = blockIdx.x * 4 + wid;
    int h = lane >> 4, c16 = lane & 15;
    constexpr int KC = CIN / 16;
    const f16* xr = xp + (size_t)node * CIN + c16 * KC;
    float s = 0.f, d = 0.f;
#pragma unroll
    for (int p = 0; p < KC / 8; ++p) {
        f16x8 v = *(const f16x8*)(xr + p * 8);
        const float* wa = &sA[h * CIN + c16 * KC + p * 8];
        const float* wd = &sD[h * CIN + c16 * KC + p * 8];
#pragma unroll
        for (int i = 0; i < 8; ++i) {
            float f = (float)v[i];
            s += f * wa[i];
            d += f * wd[i];
        }
    }
#pragma unroll
    for (int off = 1; off < 16; off <<= 1) { s += __shfl_xor(s, off); d += __shfl_xor(d, off); }
    if (c16 == 0) { als[node * 4 + h] = s; ald[node * 4 + h] = d; }
}

// ===== fused logits + softmax + input-feature aggregation, self term on-the-fly =====

template <int CIN>
__global__ __launch_bounds__(256) void k_agg2(const int* __restrict__ row_ptr,
                                              const int* __restrict__ src_sorted,
                                              const int* __restrict__ selfpos,
                                              const float* __restrict__ e4,
                                              const float* __restrict__ als,
                                              const float* __restrict__ ald,
                                              const f16* __restrict__ xp,
                                              f16* __restrict__ aggcat) {
    constexpr int EPL = CIN / 64;
    int wid = threadIdx.x >> 6, lane = threadIdx.x & 63;
    int node = blockIdx.x * 4 + wid;
    int beg = row_ptr[node], end = row_ptr[node + 1];
    int sp = selfpos[node];
    float4 ad4 = ((const float4*)ald)[node];
    const float4* e44 = (const float4*)e4;
    const float4* als4 = (const float4*)als;
    float s0 = 0.f, s1 = 0.f, s2 = 0.f, s3 = 0.f;
    float es0 = 0.f, es1 = 0.f, es2 = 0.f, es3 = 0.f;
    float a0[EPL] = {}, a1[EPL] = {}, a2[EPL] = {}, a3[EPL] = {};
    const f16* xbase = xp + lane * EPL;
#pragma unroll 4
    for (int j = beg; j < end; ++j) {
        if (j == sp) continue;
        int src = src_sorted[j];
        float4 ev = e44[j];
        es0 += ev.x; es1 += ev.y; es2 += ev.z; es3 += ev.w;
        float4 av = als4[src];
        float e0 = __expf(lrelu(ev.x + av.x + ad4.x));
        float e1 = __expf(lrelu(ev.y + av.y + ad4.y));
        float e2 = __expf(lrelu(ev.z + av.z + ad4.z));
        float e3 = __expf(lrelu(ev.w + av.w + ad4.w));
        s0 += e0; s1 += e1; s2 += e2; s3 += e3;
        const f16* xr = xbase + (size_t)src * CIN;
        if (EPL == 2) {
            f16x2 v = *(const f16x2*)xr;
            float f0 = (float)v[0], f1 = (float)v[1];
            a0[0] += e0 * f0; a0[1] += e0 * f1;
            a1[0] += e1 * f0; a1[1] += e1 * f1;
            a2[0] += e2 * f0; a2[1] += e2 * f1;
            a3[0] += e3 * f0; a3[1] += e3 * f1;
        } else {
            f16x4 v = *(const f16x4*)xr;
#pragma unroll
            for (int i = 0; i < 4; ++i) {
                float f = (float)v[i];
                a0[i] += e0 * f; a1[i] += e1 * f; a2[i] += e2 * f; a3[i] += e3 * f;
            }
        }
    }
    // self-loop: e4_self = mean of real incoming e4 (linearity of scatter-mean)
    {
        float inv = 1.f / fmaxf((float)(end - beg - 1), 1.f);
        float4 sv = als4[node];
        float e0 = __expf(lrelu(es0 * inv + sv.x + ad4.x));
        float e1 = __expf(lrelu(es1 * inv + sv.y + ad4.y));
        float e2 = __expf(lrelu(es2 * inv + sv.z + ad4.z));
        float e3 = __expf(lrelu(es3 * inv + sv.w + ad4.w));
        s0 += e0; s1 += e1; s2 += e2; s3 += e3;
        const f16* xr = xbase + (size_t)node * CIN;
        if (EPL == 2) {
            f16x2 v = *(const f16x2*)xr;
            float f0 = (float)v[0], f1 = (float)v[1];
            a0[0] += e0 * f0; a0[1] += e0 * f1;
            a1[0] += e1 * f0; a1[1] += e1 * f1;
            a2[0] += e2 * f0; a2[1] += e2 * f1;
            a3[0] += e3 * f0; a3[1] += e3 * f1;
        } else {
            f16x4 v = *(const f16x4*)xr;
#pragma unroll
            for (int i = 0; i < 4; ++i) {
                float f = (float)v[i];
                a0[i] += e0 * f; a1[i] += e1 * f; a2[i] += e2 * f; a3[i] += e3 * f;
            }
        }
    }
    float i0 = 1.f / (s0 + 1e-16f), i1 = 1.f / (s1 + 1e-16f);
    float i2 = 1.f / (s2 + 1e-16f), i3 = 1.f / (s3 + 1e-16f);
    f16* ob = aggcat + (size_t)node * 4 * CIN + lane * EPL;
    if (EPL == 2) {
        f16x2 o;
        o[0] = (f16)(a0[0] * i0); o[1] = (f16)(a0[1] * i0); *(f16x2*)(ob + 0 * CIN) = o;
        o[0] = (f16)(a1[0] * i1); o[1] = (f16)(a1[1] * i1); *(f16x2*)(ob + 1 * CIN) = o;
        o[0] = (f16)(a2[0] * i2); o[1] = (f16)(a2[1] * i2); *(f16x2*)(ob + 2 * CIN) = o;
        o[0] = (f16)(a3[0] * i3); o[1] = (f16)(a3[1] * i3); *(f16x2*)(ob + 3 * CIN) = o;
    } else {
        f16x4 o;
#pragma unroll
        for (int i = 0; i < 4; ++i) o[i] = (f16)(a0[i] * i0);
        *(f16x4*)(ob + 0 * CIN) = o;
#pragma unroll
        for (int i = 0; i < 4; ++i) o[i] = (f16)(a1[i] * i1);
        *(f16x4*)(ob + 1 * CIN) = o;
#pragma unroll
        for (int i = 0; i < 4; ++i) o[i] = (f16)(a2[i] * i2);
        *(f16x4*)(ob + 2 * CIN) = o;
#pragma unroll
        for (int i = 0; i < 4; ++i) o[i] = (f16)(a3[i] * i3);
        *(f16x4*)(ob + 3 * CIN) = o;
    }
}

// ===== MFMA GEMM, BM=32 BN=64, double-buffered reg-staged LDS, XOR swizzle =====
// hout = elu(0.25*A@Bt^T + b) [fp16], or POOL: atomicAdd mean-pool into out.

template <int K4, int C, bool POOL>
__global__ __launch_bounds__(256) void k_gemm2(const f16* __restrict__ A,
                                               const f16* __restrict__ Bt,
                                               const float* __restrict__ bias,
                                               f16* __restrict__ hout,
                                               const int* __restrict__ batch,
                                               const float* __restrict__ invc,
                                               float* __restrict__ out) {
    constexpr int NS = K4 / 32;
    __shared__ f16 Als[2][32 * 32];
    __shared__ f16 Bls[2][64 * 32];
    int bm = blockIdx.x * 32, bn = blockIdx.y * 64;
    int tid = threadIdx.x;
    int wid = tid >> 6, lane = tid & 63;
    int mq = wid >> 1, nq = wid & 1;
    int fr = lane & 15, kc = lane >> 4;

    int ar = tid >> 2, ac = tid & 3;                     // stage coords
    const f16* Ap = A + (size_t)(bm + (ar & 31)) * K4 + ac * 8;
    const f16* Bp = Bt + (size_t)(bn + ar) * K4 + ac * 8;
    bool aok = (tid < 128) && (bm + ar < NN);
    int wA = (ar & 31) * 32 + ((ac ^ (ar & 3)) * 8);     // swizzled write offsets
    int wB = ar * 32 + ((ac ^ (ar & 3)) * 8);
    int kx = (kc ^ (fr & 3)) * 8;                        // swizzled read k-offset
    int rA = (mq * 16 + fr) * 32 + kx;
    int rB0 = (nq * 32 + fr) * 32 + kx;
    int rB1 = rB0 + 16 * 32;

    f32x4 acc0 = (f32x4){0.f, 0.f, 0.f, 0.f};
    f32x4 acc1 = (f32x4){0.f, 0.f, 0.f, 0.f};

    u16x8 va = (u16x8)0, vb;
    if (aok) va = *(const u16x8*)Ap;
    vb = *(const u16x8*)Bp;
    if (tid < 128) *(u16x8*)&Als[0][wA] = va;
    *(u16x8*)&Bls[0][wB] = vb;
    __syncthreads();

#pragma unroll
    for (int s = 0; s < NS; ++s) {
        int cur = s & 1;
        if (s + 1 < NS) {
            va = (u16x8)0;
            if (aok) va = *(const u16x8*)(Ap + (s + 1) * 32);
            vb = *(const u16x8*)(Bp + (s + 1) * 32);
        }
        f16x8 af  = *(const f16x8*)&Als[cur][rA];
        f16x8 bf0 = *(const f16x8*)&Bls[cur][rB0];
        f16x8 bf1 = *(const f16x8*)&Bls[cur][rB1];
        acc0 = __builtin_amdgcn_mfma_f32_16x16x32_f16(af, bf0, acc0, 0, 0, 0);
        acc1 = __builtin_amdgcn_mfma_f32_16x16x32_f16(af, bf1, acc1, 0, 0, 0);
        if (s + 1 < NS) {
            if (tid < 128) *(u16x8*)&Als[cur ^ 1][wA] = va;
            *(u16x8*)&Bls[cur ^ 1][wB] = vb;
        }
        __syncthreads();
    }

    int cr = kc * 4, cc = fr;
    int col0 = bn + nq * 32 + cc, col1 = col0 + 16;
    float b0 = bias[col0], b1 = bias[col1];
#pragma unroll
    for (int r = 0; r < 4; ++r) {
        int row = bm + mq * 16 + cr + r;
        if (row >= NN) continue;
        float v0 = elu1(0.25f * acc0[r] + b0);
        float v1 = elu1(0.25f * acc1[r] + b1);
        if (POOL) {
            int g = batch[row];
            float ic = invc[g];
            atomicAdd(&out[(size_t)g * C + col0], v0 * ic);
            atomicAdd(&out[(size_t)g * C + col1], v1 * ic);
        } else {
            f16* cp = hout + (size_t)row * C + col0;
            cp[0] = (f16)v0;
            cp[16] = (f16)v1;
        }
    }
}

// ============================ host side ============================

struct Ws {
    f16 *x16, *hA, *hB, *aggcat, *Wt1, *Wt2, *Wt3;
    float *als1, *ald1, *als2, *ald2, *als3, *ald3;
    float *e4all, *asd1, *asd2, *asd3, *Wf1, *Wf2, *Wf3, *invc;
    int *deg, *row_ptr, *cursor, *src_sorted, *selfpos;
};

static void carve(void* base, Ws& w) {
    char* p = (char*)base;
    size_t off = 0;
    auto take = [&](size_t bytes) {
        off = (off + 255) & ~(size_t)255;
        void* r = p + off;
        off += bytes;
        return r;
    };
    w.x16        = (f16*)take((size_t)NN * 128 * 2);
    w.hA         = (f16*)take((size_t)NN * 128 * 2);
    w.hB         = (f16*)take((size_t)NN * 256 * 2);
    w.aggcat     = (f16*)take((size_t)NN * 1024 * 2);
    w.Wt1        = (f16*)take((size_t)512 * 128 * 2);
    w.Wt2        = (f16*)take((size_t)512 * 256 * 2);
    w.Wt3        = (f16*)take((size_t)1024 * 128 * 2);
    w.als1       = (float*)take((size_t)NN * 4 * 4);
    w.ald1       = (float*)take((size_t)NN * 4 * 4);
    w.als2       = (float*)take((size_t)NN * 4 * 4);
    w.ald2       = (float*)take((size_t)NN * 4 * 4);
    w.als3       = (float*)take((size_t)NN * 4 * 4);
    w.ald3       = (float*)take((size_t)NN * 4 * 4);
    w.e4all      = (float*)take((size_t)3 * NE2 * 4 * 4);
    w.asd1       = (float*)take(2 * 4 * 128 * 4);
    w.asd2       = (float*)take(2 * 4 * 128 * 4);
    w.asd3       = (float*)take(2 * 4 * 256 * 4);
    w.Wf1        = (float*)take(128 * 4);
    w.Wf2        = (float*)take(128 * 4);
    w.Wf3        = (float*)take(128 * 4);
    w.invc       = (float*)take(NG * 4);
    w.deg        = (int*)take((size_t)NN * 4);
    w.row_ptr    = (int*)take((size_t)(NN + 1) * 4);
    w.cursor     = (int*)take((size_t)NN * 4);
    w.src_sorted = (int*)take((size_t)NE2 * 4);
    w.selfpos    = (int*)take((size_t)NN * 4);
}

extern "C" void kernel_launch(void* const* d_in, const int* in_sizes, int n_in,
                              void* d_out, int out_size, void* d_ws, size_t ws_size,
                              hipStream_t stream) {
    const float* x     = (const float*)d_in[0];
    const int*   ei    = (const int*)d_in[1];
    const float* eattr = (const float*)d_in[2];
    const int*   batch = (const int*)d_in[3];
    const float* W[3]  = {(const float*)d_in[4],  (const float*)d_in[10], (const float*)d_in[16]};
    const float* We[3] = {(const float*)d_in[5],  (const float*)d_in[11], (const float*)d_in[17]};
    const float* as_[3]= {(const float*)d_in[6],  (const float*)d_in[12], (const float*)d_in[18]};
    const float* ad_[3]= {(const float*)d_in[7],  (const float*)d_in[13], (const float*)d_in[19]};
    const float* ae_[3]= {(const float*)d_in[8],  (const float*)d_in[14], (const float*)d_in[20]};
    const float* b_[3] = {(const float*)d_in[9],  (const float*)d_in[15], (const float*)d_in[21]};
    float* out = (float*)d_out;

    Ws w;
    carve(d_ws, w);

    hipMemsetAsync(w.deg, 0, (size_t)NN * 4, stream);
    hipMemsetAsync(out, 0, (size_t)NG * 128 * 4, stream);

    // ---- init: weight prep + deg + x cast + group inv-counts ----
    k_init<<<2207, 256, 0, stream>>>(
        W[0], We[0], as_[0], ad_[0], ae_[0], w.Wt1, w.asd1, w.Wf1,
        W[1], We[1], as_[1], ad_[1], ae_[1], w.Wt2, w.asd2, w.Wf2,
        W[2], We[2], as_[2], ad_[2], ae_[2], w.Wt3, w.asd3, w.Wf3,
        ei, w.deg, x, w.x16, batch, w.invc);

    k_scan2<<<1, 1024, 0, stream>>>(w.deg, w.row_ptr, w.cursor);

    // ---- CSR fill + real-edge e4 + layer-1 alnode ----
    k_fill_e4<<<3165, 256, 0, stream>>>(ei, w.cursor, w.src_sorted, w.selfpos, eattr,
                                        w.Wf1, w.Wf2, w.Wf3, w.e4all,
                                        w.x16, w.asd1, w.als1, w.ald1);

    const float* e4_1 = w.e4all;
    const float* e4_2 = w.e4all + (size_t)NE2 * 4;
    const float* e4_3 = w.e4all + (size_t)2 * NE2 * 4;

    // ---- layer 1 ----
    k_agg2<128><<<NN / 4, 256, 0, stream>>>(w.row_ptr, w.src_sorted, w.selfpos, e4_1,
                                            w.als1, w.ald1, w.x16, w.aggcat);
    k_gemm2<512, 128, false><<<dim3(313, 2), 256, 0, stream>>>(w.aggcat, w.Wt1, b_[0],
                                                               w.hA, nullptr, nullptr, nullptr);
    // ---- layer 2 ----
    k_alnode2<128><<<NN / 4, 256, 0, stream>>>(w.hA, w.asd2, w.als2, w.ald2);
    k_agg2<128><<<NN / 4, 256, 0, stream>>>(w.row_ptr, w.src_sorted, w.selfpos, e4_2,
                                            w.als2, w.ald2, w.hA, w.aggcat);
    k_gemm2<512, 256, false><<<dim3(313, 4), 256, 0, stream>>>(w.aggcat, w.Wt2, b_[1],
                                                               w.hB, nullptr, nullptr, nullptr);
    // ---- layer 3 + fused mean-pool ----
    k_alnode2<256><<<NN / 4, 256, 0, stream>>>(w.hB, w.asd3, w.als3, w.ald3);
    k_agg2<256><<<NN / 4, 256, 0, stream>>>(w.row_ptr, w.src_sorted, w.selfpos, e4_3,
                                            w.als3, w.ald3, w.hB, w.aggcat);
    k_gemm2<1024, 128, true><<<dim3(313, 2), 256, 0, stream>>>(w.aggcat, w.Wt3, b_[2],
                                                               nullptr, batch, w.invc, out);
}

// Round 9
// 316.602 us; speedup vs baseline: 1.1485x; 1.0058x over previous
//
#include <hip/hip_runtime.h>

#define NN 10000
#define NE 160000
#define NE2 (NE + NN)
#define NG 64
#define EDIM 32

typedef _Float16 f16;
typedef __attribute__((ext_vector_type(2))) _Float16 f16x2;
typedef __attribute__((ext_vector_type(4))) _Float16 f16x4;
typedef __attribute__((ext_vector_type(8))) _Float16 f16x8;
typedef __attribute__((ext_vector_type(4))) float f32x4;
typedef __attribute__((ext_vector_type(8))) unsigned short u16x8;

__device__ __forceinline__ float lrelu(float x) { return fmaxf(x, 0.2f * x); }
__device__ __forceinline__ float elu1(float x) { return x > 0.f ? x : __expf(x) - 1.f; }

// ========== weight prep body ==========

template <int CIN, int C>
__device__ __forceinline__ void wprep_body(int b, int tid,
                                           const float* __restrict__ W,
                                           const float* __restrict__ We,
                                           const float* __restrict__ as_,
                                           const float* __restrict__ ad_,
                                           const float* __restrict__ ae_,
                                           f16* __restrict__ Bt,
                                           float* __restrict__ asd,
                                           float* __restrict__ Wf,
                                           float (*t)[33]) {
    constexpr int K4 = 4 * CIN;
    constexpr int KT = CIN / 32, CT = C / 32;
    constexpr int TB = 4 * KT * CT;
    constexpr int FB = CIN / 64;
    if (b < TB) {
        int h = b / (KT * CT);
        int rem = b % (KT * CT);
        int k0 = (rem / CT) * 32, c0 = (rem % CT) * 32;
        int i = tid >> 5, j = tid & 31;
#pragma unroll
        for (int it = 0; it < 4; ++it)
            t[i + it * 8][j] = W[(size_t)(k0 + i + it * 8) * (4 * C) + h * C + c0 + j];
        __syncthreads();
#pragma unroll
        for (int it = 0; it < 4; ++it) {
            int jj = (tid >> 5) + it * 8, ii = tid & 31;
            Bt[(size_t)(c0 + jj) * K4 + h * CIN + k0 + ii] = (f16)t[ii][jj];
        }
    } else if (b < TB + FB) {
        int k = (b - TB) * 64 + (tid >> 2), h = tid & 3;
        const float4* wr = (const float4*)(W + (size_t)k * (4 * C) + h * C);
        const float4* a4 = (const float4*)(as_ + h * C);
        const float4* d4 = (const float4*)(ad_ + h * C);
        float s = 0.f, d = 0.f;
        for (int c = 0; c < C / 4; ++c) {
            float4 w = wr[c], av = a4[c], dv = d4[c];
            s += w.x * av.x + w.y * av.y + w.z * av.z + w.w * av.w;
            d += w.x * dv.x + w.y * dv.y + w.z * dv.z + w.w * dv.w;
        }
        asd[h * CIN + k] = s;
        asd[4 * CIN + h * CIN + k] = d;
    } else if (tid < 128) {
        int dd = tid >> 2, h = tid & 3;
        const float4* wr = (const float4*)(We + (size_t)dd * (4 * C) + h * C);
        const float4* a4 = (const float4*)(ae_ + h * C);
        float s = 0.f;
        for (int c = 0; c < C / 4; ++c) {
            float4 w = wr[c], av = a4[c];
            s += w.x * av.x + w.y * av.y + w.z * av.z + w.w * av.w;
        }
        Wf[dd * 4 + h] = s;
    }
}

// ===== k_init: wprep(331) | deg atomics(625) | x cast(1250) | invc(1) =====

__global__ __launch_bounds__(256) void k_init(
    const float* W1, const float* We1, const float* as1, const float* ad1, const float* ae1,
    f16* Bt1, float* asd1, float* Wf1,
    const float* W2, const float* We2, const float* as2, const float* ad2, const float* ae2,
    f16* Bt2, float* asd2, float* Wf2,
    const float* W3, const float* We3, const float* as3, const float* ad3, const float* ae3,
    f16* Bt3, float* asd3, float* Wf3,
    const int* ei, int* deg, const float* x, f16* x16,
    const int* batch, float* invc) {
    __shared__ float t[32][33];
    int b = blockIdx.x, tid = threadIdx.x;
    if (b < 67) {
        wprep_body<128, 128>(b, tid, W1, We1, as1, ad1, ae1, Bt1, asd1, Wf1, t);
    } else if (b < 198) {
        wprep_body<128, 256>(b - 67, tid, W2, We2, as2, ad2, ae2, Bt2, asd2, Wf2, t);
    } else if (b < 331) {
        wprep_body<256, 128>(b - 198, tid, W3, We3, as3, ad3, ae3, Bt3, asd3, Wf3, t);
    } else if (b < 956) {
        int e = (b - 331) * 256 + tid;
        atomicAdd(&deg[ei[NE + e]], 1);
    } else if (b < 2206) {
        int i = (b - 956) * 256 + tid;
        float4 v = ((const float4*)x)[i];
        f16x4 o;
        o[0] = (f16)v.x; o[1] = (f16)v.y; o[2] = (f16)v.z; o[3] = (f16)v.w;
        *(f16x4*)(x16 + i * 4) = o;
    } else if (tid < NG) {
        int g = tid;
        int lo = 0, hi = NN;
        while (lo < hi) { int mid = (lo + hi) >> 1; if (batch[mid] < g) lo = mid + 1; else hi = mid; }
        int start = lo;
        lo = start; hi = NN;
        while (lo < hi) { int mid = (lo + hi) >> 1; if (batch[mid] < g + 1) lo = mid + 1; else hi = mid; }
        invc[g] = 1.f / fmaxf((float)(lo - start), 1.f);
    }
}

// ============== scan (row_ptr/cursor) ==============

__global__ __launch_bounds__(1024) void k_scan2(const int* __restrict__ deg,
                                                int* __restrict__ row_ptr,
                                                int* __restrict__ cursor) {
    int tid = threadIdx.x;
    int vals[10];
    int run = 0;
#pragma unroll
    for (int i = 0; i < 10; ++i) {
        int n = tid * 10 + i;
        int v = (n < NN) ? (deg[n] + 1) : 0;
        run += v;
        vals[i] = run;
    }
    int total = run;
    int lane = tid & 63, wid = tid >> 6;
    int sc = total;
#pragma unroll
    for (int off = 1; off < 64; off <<= 1) {
        int t = __shfl_up(sc, off);
        if (lane >= off) sc += t;
    }
    __shared__ int wsum[16];
    if (lane == 63) wsum[wid] = sc;
    __syncthreads();
    if (tid == 0) {
        int a = 0;
#pragma unroll
        for (int w = 0; w < 16; ++w) { int t = wsum[w]; wsum[w] = a; a += t; }
    }
    __syncthreads();
    int excl = sc - total + wsum[wid];
#pragma unroll
    for (int i = 0; i < 10; ++i) {
        int n = tid * 10 + i;
        if (n < NN) {
            int prev = i ? vals[i - 1] : 0;
            row_ptr[n + 1] = excl + vals[i];
            cursor[n] = excl + prev;
        }
    }
    if (tid == 0) row_ptr[0] = 0;
}

// ===== k_fill_e4: CSR fill + real-edge e4 (665 blocks) | layer-1 alnode (2500) =====

__global__ __launch_bounds__(256) void k_fill_e4(const int* __restrict__ ei,
                                                 int* __restrict__ cursor,
                                                 int* __restrict__ src_sorted,
                                                 int* __restrict__ selfpos,
                                                 const float* __restrict__ eattr,
                                                 const float* __restrict__ Wf1,
                                                 const float* __restrict__ Wf2,
                                                 const float* __restrict__ Wf3,
                                                 float* __restrict__ e4all,
                                                 const f16* __restrict__ x16,
                                                 const float* __restrict__ asd1,
                                                 float* __restrict__ als1,
                                                 float* __restrict__ ald1) {
    __shared__ float smem[1024];
    int b = blockIdx.x, tid = threadIdx.x;
    if (b < 665) {
        for (int i = tid; i < 384; i += 256)
            smem[i] = (i < 128) ? Wf1[i] : (i < 256) ? Wf2[i - 128] : Wf3[i - 256];
        __syncthreads();
        int e = b * 256 + tid;
        if (e >= NE2) return;
        if (e < NE) {
            int s = ei[e], d = ei[NE + e];
            int p = atomicAdd(&cursor[d], 1);
            src_sorted[p] = s;
            float4 v[8];
            const float4* er = (const float4*)(eattr + (size_t)e * EDIM);
#pragma unroll
            for (int i = 0; i < 8; ++i) v[i] = er[i];
#pragma unroll
            for (int l = 0; l < 3; ++l) {
                float a0 = 0.f, a1 = 0.f, a2 = 0.f, a3 = 0.f;
#pragma unroll
                for (int d4 = 0; d4 < 8; ++d4) {
                    const float* w = &smem[l * 128 + d4 * 16];
                    a0 += v[d4].x * w[0] + v[d4].y * w[4] + v[d4].z * w[8]  + v[d4].w * w[12];
                    a1 += v[d4].x * w[1] + v[d4].y * w[5] + v[d4].z * w[9]  + v[d4].w * w[13];
                    a2 += v[d4].x * w[2] + v[d4].y * w[6] + v[d4].z * w[10] + v[d4].w * w[14];
                    a3 += v[d4].x * w[3] + v[d4].y * w[7] + v[d4].z * w[11] + v[d4].w * w[15];
                }
                ((float4*)e4all)[(size_t)l * NE2 + p] = make_float4(a0, a1, a2, a3);
            }
        } else {
            int n = e - NE;
            int p = atomicAdd(&cursor[n], 1);
            src_sorted[p] = n;
            selfpos[n] = p;
        }
    } else {
        float* sA = smem;
        float* sD = smem + 512;
        for (int i = tid; i < 512; i += 256) { sA[i] = asd1[i]; sD[i] = asd1[512 + i]; }
        __syncthreads();
        int wid = tid >> 6, lane = tid & 63;
        int node = (b - 665) * 4 + wid;
        int h = lane >> 4, c16 = lane & 15;
        const f16* xr = x16 + (size_t)node * 128 + c16 * 8;
        f16x8 v = *(const f16x8*)xr;
        float s = 0.f, d = 0.f;
#pragma unroll
        for (int i = 0; i < 8; ++i) {
            float f = (float)v[i];
            s += f * sA[h * 128 + c16 * 8 + i];
            d += f * sD[h * 128 + c16 * 8 + i];
        }
#pragma unroll
        for (int off = 1; off < 16; off <<= 1) { s += __shfl_xor(s, off); d += __shfl_xor(d, off); }
        if (c16 == 0) { als1[node * 4 + h] = s; ald1[node * 4 + h] = d; }
    }
}

// ===== alnode: als[n,h] = h[n]·âs[h] (layers 2/3) =====

template <int CIN>
__global__ __launch_bounds__(256) void k_alnode2(const f16* __restrict__ xp,
                                                 const float* __restrict__ asd,
                                                 float* __restrict__ als,
                                                 float* __restrict__ ald) {
    __shared__ float sA[4 * CIN], sD[4 * CIN];
    for (int i = threadIdx.x; i < 4 * CIN; i += 256) { sA[i] = asd[i]; sD[i] = asd[4 * CIN + i]; }
    __syncthreads();
    int wid = threadIdx.x >> 6, lane = threadIdx.x & 63;
    int node = blockIdx.x * 4 + wid;
    int h = lane >> 4, c16 = lane & 15;
    constexpr int KC = CIN / 16;
    const f16* xr = xp + (size_t)node * CIN + c16 * KC;
    float s = 0.f, d = 0.f;
#pragma unroll
    for (int p = 0; p < KC / 8; ++p) {
        f16x8 v = *(const f16x8*)(xr + p * 8);
        const float* wa = &sA[h * CIN + c16 * KC + p * 8];
        const float* wd = &sD[h * CIN + c16 * KC + p * 8];
#pragma unroll
        for (int i = 0; i < 8; ++i) {
            float f = (float)v[i];
            s += f * wa[i];
            d += f * wd[i];
        }
    }
#pragma unroll
    for (int off = 1; off < 16; off <<= 1) { s += __shfl_xor(s, off); d += __shfl_xor(d, off); }
    if (c16 == 0) { als[node * 4 + h] = s; ald[node * 4 + h] = d; }
}

// ===== fused logits + softmax + input-feature aggregation, self term on-the-fly =====
// WPN waves per node; each wave owns a CIN/WPN column chunk (exp chain recomputed
// per wave — wave-uniform, no cross-wave reduce needed).

template <int CIN, int WPN>
__global__ __launch_bounds__(256) void k_agg2(const int* __restrict__ row_ptr,
                                              const int* __restrict__ src_sorted,
                                              const int* __restrict__ selfpos,
                                              const float* __restrict__ e4,
                                              const float* __restrict__ als,
                                              const float* __restrict__ ald,
                                              const f16* __restrict__ xp,
                                              f16* __restrict__ aggcat) {
    constexpr int CHUNK = CIN / WPN;
    constexpr int EPL = CHUNK / 64;   // 2 in all instantiations
    constexpr int NPB = 4 / WPN;
    int wid = threadIdx.x >> 6, lane = threadIdx.x & 63;
    int node = blockIdx.x * NPB + wid / WPN;
    int half = wid % WPN;
    int beg = row_ptr[node], end = row_ptr[node + 1];
    int sp = selfpos[node];
    float4 ad4 = ((const float4*)ald)[node];
    const float4* e44 = (const float4*)e4;
    const float4* als4 = (const float4*)als;
    float s0 = 0.f, s1 = 0.f, s2 = 0.f, s3 = 0.f;
    float es0 = 0.f, es1 = 0.f, es2 = 0.f, es3 = 0.f;
    float a0[EPL] = {}, a1[EPL] = {}, a2[EPL] = {}, a3[EPL] = {};
    const f16* xbase = xp + half * CHUNK + lane * EPL;
#pragma unroll 4
    for (int j = beg; j < end; ++j) {
        if (j == sp) continue;
        int src = src_sorted[j];
        float4 ev = e44[j];
        es0 += ev.x; es1 += ev.y; es2 += ev.z; es3 += ev.w;
        float4 av = als4[src];
        float e0 = __expf(lrelu(ev.x + av.x + ad4.x));
        float e1 = __expf(lrelu(ev.y + av.y + ad4.y));
        float e2 = __expf(lrelu(ev.z + av.z + ad4.z));
        float e3 = __expf(lrelu(ev.w + av.w + ad4.w));
        s0 += e0; s1 += e1; s2 += e2; s3 += e3;
        const f16* xr = xbase + (size_t)src * CIN;
        f16x2 v = *(const f16x2*)xr;
        float f0 = (float)v[0], f1 = (float)v[1];
        a0[0] += e0 * f0; a0[1] += e0 * f1;
        a1[0] += e1 * f0; a1[1] += e1 * f1;
        a2[0] += e2 * f0; a2[1] += e2 * f1;
        a3[0] += e3 * f0; a3[1] += e3 * f1;
    }
    // self-loop: e4_self = mean of real incoming e4 (linearity of scatter-mean)
    {
        float inv = 1.f / fmaxf((float)(end - beg - 1), 1.f);
        float4 sv = als4[node];
        float e0 = __expf(lrelu(es0 * inv + sv.x + ad4.x));
        float e1 = __expf(lrelu(es1 * inv + sv.y + ad4.y));
        float e2 = __expf(lrelu(es2 * inv + sv.z + ad4.z));
        float e3 = __expf(lrelu(es3 * inv + sv.w + ad4.w));
        s0 += e0; s1 += e1; s2 += e2; s3 += e3;
        const f16* xr = xbase + (size_t)node * CIN;
        f16x2 v = *(const f16x2*)xr;
        float f0 = (float)v[0], f1 = (float)v[1];
        a0[0] += e0 * f0; a0[1] += e0 * f1;
        a1[0] += e1 * f0; a1[1] += e1 * f1;
        a2[0] += e2 * f0; a2[1] += e2 * f1;
        a3[0] += e3 * f0; a3[1] += e3 * f1;
    }
    float i0 = 1.f / (s0 + 1e-16f), i1 = 1.f / (s1 + 1e-16f);
    float i2 = 1.f / (s2 + 1e-16f), i3 = 1.f / (s3 + 1e-16f);
    f16* ob = aggcat + (size_t)node * 4 * CIN + half * CHUNK + lane * EPL;
    f16x2 o;
    o[0] = (f16)(a0[0] * i0); o[1] = (f16)(a0[1] * i0); *(f16x2*)(ob + 0 * CIN) = o;
    o[0] = (f16)(a1[0] * i1); o[1] = (f16)(a1[1] * i1); *(f16x2*)(ob + 1 * CIN) = o;
    o[0] = (f16)(a2[0] * i2); o[1] = (f16)(a2[1] * i2); *(f16x2*)(ob + 2 * CIN) = o;
    o[0] = (f16)(a3[0] * i3); o[1] = (f16)(a3[1] * i3); *(f16x2*)(ob + 3 * CIN) = o;
}

// ===== MFMA GEMM, BM=32 BN=64, double-buffered reg-staged LDS, XOR swizzle =====
// hout = elu(0.25*A@Bt^T + b) [fp16]; POOL: LDS group-window mean-pool into out.

template <int K4, int C, bool POOL>
__global__ __launch_bounds__(256) void k_gemm2(const f16* __restrict__ A,
                                               const f16* __restrict__ Bt,
                                               const float* __restrict__ bias,
                                               f16* __restrict__ hout,
                                               const int* __restrict__ batch,
                                               const float* __restrict__ invc,
                                               float* __restrict__ out) {
    constexpr int NS = K4 / 32;
    __shared__ f16 Als[2][32 * 32];
    __shared__ f16 Bls[2][64 * 32];
    __shared__ float pacc[4][64];     // POOL: group-window accumulators
    int bm = blockIdx.x * 32, bn = blockIdx.y * 64;
    int tid = threadIdx.x;
    int wid = tid >> 6, lane = tid & 63;
    int mq = wid >> 1, nq = wid & 1;
    int fr = lane & 15, kc = lane >> 4;

    if (POOL) pacc[tid >> 6][tid & 63] = 0.f;

    int ar = tid >> 2, ac = tid & 3;                     // stage coords
    const f16* Ap = A + (size_t)(bm + (ar & 31)) * K4 + ac * 8;
    const f16* Bp = Bt + (size_t)(bn + ar) * K4 + ac * 8;
    bool aok = (tid < 128) && (bm + ar < NN);
    int wA = (ar & 31) * 32 + ((ac ^ (ar & 3)) * 8);     // swizzled write offsets
    int wB = ar * 32 + ((ac ^ (ar & 3)) * 8);
    int kx = (kc ^ (fr & 3)) * 8;                        // swizzled read k-offset
    int rA = (mq * 16 + fr) * 32 + kx;
    int rB0 = (nq * 32 + fr) * 32 + kx;
    int rB1 = rB0 + 16 * 32;

    f32x4 acc0 = (f32x4){0.f, 0.f, 0.f, 0.f};
    f32x4 acc1 = (f32x4){0.f, 0.f, 0.f, 0.f};

    u16x8 va = (u16x8)0, vb;
    if (aok) va = *(const u16x8*)Ap;
    vb = *(const u16x8*)Bp;
    if (tid < 128) *(u16x8*)&Als[0][wA] = va;
    *(u16x8*)&Bls[0][wB] = vb;
    __syncthreads();

#pragma unroll
    for (int s = 0; s < NS; ++s) {
        int cur = s & 1;
        if (s + 1 < NS) {
            va = (u16x8)0;
            if (aok) va = *(const u16x8*)(Ap + (s + 1) * 32);
            vb = *(const u16x8*)(Bp + (s + 1) * 32);
        }
        f16x8 af  = *(const f16x8*)&Als[cur][rA];
        f16x8 bf0 = *(const f16x8*)&Bls[cur][rB0];
        f16x8 bf1 = *(const f16x8*)&Bls[cur][rB1];
        acc0 = __builtin_amdgcn_mfma_f32_16x16x32_f16(af, bf0, acc0, 0, 0, 0);
        acc1 = __builtin_amdgcn_mfma_f32_16x16x32_f16(af, bf1, acc1, 0, 0, 0);
        if (s + 1 < NS) {
            if (tid < 128) *(u16x8*)&Als[cur ^ 1][wA] = va;
            *(u16x8*)&Bls[cur ^ 1][wB] = vb;
        }
        __syncthreads();
    }

    int cr = kc * 4, cc = fr;
    int lc0 = nq * 32 + cc, lc1 = lc0 + 16;              // local cols in [0,64)
    int col0 = bn + lc0, col1 = bn + lc1;
    float b0 = bias[col0], b1 = bias[col1];
    int g0 = POOL ? batch[bm] : 0;
#pragma unroll
    for (int r = 0; r < 4; ++r) {
        int row = bm + mq * 16 + cr + r;
        if (row >= NN) continue;
        float v0 = elu1(0.25f * acc0[r] + b0);
        float v1 = elu1(0.25f * acc1[r] + b1);
        if (POOL) {
            int g = batch[row];
            float ic = invc[g];
            int wi = g - g0;
            if (wi < 4) {
                atomicAdd(&pacc[wi][lc0], v0 * ic);
                atomicAdd(&pacc[wi][lc1], v1 * ic);
            } else {  // rare fallback: tile spans >4 groups
                atomicAdd(&out[(size_t)g * C + col0], v0 * ic);
                atomicAdd(&out[(size_t)g * C + col1], v1 * ic);
            }
        } else {
            f16* cp = hout + (size_t)row * C + col0;
            cp[0] = (f16)v0;
            cp[16] = (f16)v1;
        }
    }
    if (POOL) {
        __syncthreads();
        int wi = tid >> 6, c = tid & 63;
        float val = pacc[wi][c];
        int g = g0 + wi;
        if (val != 0.f && g < NG)
            atomicAdd(&out[(size_t)g * C + bn + c], val);
    }
}

// ============================ host side ============================

struct Ws {
    f16 *x16, *hA, *hB, *aggcat, *Wt1, *Wt2, *Wt3;
    float *als1, *ald1, *als2, *ald2, *als3, *ald3;
    float *e4all, *asd1, *asd2, *asd3, *Wf1, *Wf2, *Wf3, *invc;
    int *deg, *row_ptr, *cursor, *src_sorted, *selfpos;
};

static void carve(void* base, Ws& w) {
    char* p = (char*)base;
    size_t off = 0;
    auto take = [&](size_t bytes) {
        off = (off + 255) & ~(size_t)255;
        void* r = p + off;
        off += bytes;
        return r;
    };
    w.x16        = (f16*)take((size_t)NN * 128 * 2);
    w.hA         = (f16*)take((size_t)NN * 128 * 2);
    w.hB         = (f16*)take((size_t)NN * 256 * 2);
    w.aggcat     = (f16*)take((size_t)NN * 1024 * 2);
    w.Wt1        = (f16*)take((size_t)512 * 128 * 2);
    w.Wt2        = (f16*)take((size_t)512 * 256 * 2);
    w.Wt3        = (f16*)take((size_t)1024 * 128 * 2);
    w.als1       = (float*)take((size_t)NN * 4 * 4);
    w.ald1       = (float*)take((size_t)NN * 4 * 4);
    w.als2       = (float*)take((size_t)NN * 4 * 4);
    w.ald2       = (float*)take((size_t)NN * 4 * 4);
    w.als3       = (float*)take((size_t)NN * 4 * 4);
    w.ald3       = (float*)take((size_t)NN * 4 * 4);
    w.e4all      = (float*)take((size_t)3 * NE2 * 4 * 4);
    w.asd1       = (float*)take(2 * 4 * 128 * 4);
    w.asd2       = (float*)take(2 * 4 * 128 * 4);
    w.asd3       = (float*)take(2 * 4 * 256 * 4);
    w.Wf1        = (float*)take(128 * 4);
    w.Wf2        = (float*)take(128 * 4);
    w.Wf3        = (float*)take(128 * 4);
    w.invc       = (float*)take(NG * 4);
    w.deg        = (int*)take((size_t)NN * 4);
    w.row_ptr    = (int*)take((size_t)(NN + 1) * 4);
    w.cursor     = (int*)take((size_t)NN * 4);
    w.src_sorted = (int*)take((size_t)NE2 * 4);
    w.selfpos    = (int*)take((size_t)NN * 4);
}

extern "C" void kernel_launch(void* const* d_in, const int* in_sizes, int n_in,
                              void* d_out, int out_size, void* d_ws, size_t ws_size,
                              hipStream_t stream) {
    const float* x     = (const float*)d_in[0];
    const int*   ei    = (const int*)d_in[1];
    const float* eattr = (const float*)d_in[2];
    const int*   batch = (const int*)d_in[3];
    const float* W[3]  = {(const float*)d_in[4],  (const float*)d_in[10], (const float*)d_in[16]};
    const float* We[3] = {(const float*)d_in[5],  (const float*)d_in[11], (const float*)d_in[17]};
    const float* as_[3]= {(const float*)d_in[6],  (const float*)d_in[12], (const float*)d_in[18]};
    const float* ad_[3]= {(const float*)d_in[7],  (const float*)d_in[13], (const float*)d_in[19]};
    const float* ae_[3]= {(const float*)d_in[8],  (const float*)d_in[14], (const float*)d_in[20]};
    const float* b_[3] = {(const float*)d_in[9],  (const float*)d_in[15], (const float*)d_in[21]};
    float* out = (float*)d_out;

    Ws w;
    carve(d_ws, w);

    hipMemsetAsync(w.deg, 0, (size_t)NN * 4, stream);
    hipMemsetAsync(out, 0, (size_t)NG * 128 * 4, stream);

    // ---- init: weight prep + deg + x cast + group inv-counts ----
    k_init<<<2207, 256, 0, stream>>>(
        W[0], We[0], as_[0], ad_[0], ae_[0], w.Wt1, w.asd1, w.Wf1,
        W[1], We[1], as_[1], ad_[1], ae_[1], w.Wt2, w.asd2, w.Wf2,
        W[2], We[2], as_[2], ad_[2], ae_[2], w.Wt3, w.asd3, w.Wf3,
        ei, w.deg, x, w.x16, batch, w.invc);

    k_scan2<<<1, 1024, 0, stream>>>(w.deg, w.row_ptr, w.cursor);

    // ---- CSR fill + real-edge e4 + layer-1 alnode ----
    k_fill_e4<<<3165, 256, 0, stream>>>(ei, w.cursor, w.src_sorted, w.selfpos, eattr,
                                        w.Wf1, w.Wf2, w.Wf3, w.e4all,
                                        w.x16, w.asd1, w.als1, w.ald1);

    const float* e4_1 = w.e4all;
    const float* e4_2 = w.e4all + (size_t)NE2 * 4;
    const float* e4_3 = w.e4all + (size_t)2 * NE2 * 4;

    // ---- layer 1 ----
    k_agg2<128, 1><<<NN / 4, 256, 0, stream>>>(w.row_ptr, w.src_sorted, w.selfpos, e4_1,
                                               w.als1, w.ald1, w.x16, w.aggcat);
    k_gemm2<512, 128, false><<<dim3(313, 2), 256, 0, stream>>>(w.aggcat, w.Wt1, b_[0],
                                                               w.hA, nullptr, nullptr, nullptr);
    // ---- layer 2 ----
    k_alnode2<128><<<NN / 4, 256, 0, stream>>>(w.hA, w.asd2, w.als2, w.ald2);
    k_agg2<128, 1><<<NN / 4, 256, 0, stream>>>(w.row_ptr, w.src_sorted, w.selfpos, e4_2,
                                               w.als2, w.ald2, w.hA, w.aggcat);
    k_gemm2<512, 256, false><<<dim3(313, 4), 256, 0, stream>>>(w.aggcat, w.Wt2, b_[1],
                                                               w.hB, nullptr, nullptr, nullptr);
    // ---- layer 3 + fused mean-pool (2 waves per node in agg) ----
    k_alnode2<256><<<NN / 4, 256, 0, stream>>>(w.hB, w.asd3, w.als3, w.ald3);
    k_agg2<256, 2><<<NN / 2, 256, 0, stream>>>(w.row_ptr, w.src_sorted, w.selfpos, e4_3,
                                               w.als3, w.ald3, w.hB, w.aggcat);
    k_gemm2<1024, 128, true><<<dim3(313, 2), 256, 0, stream>>>(w.aggcat, w.Wt3, b_[2],
                                                               nullptr, batch, w.invc, out);
}

// Round 10
// 288.267 us; speedup vs baseline: 1.2614x; 1.0983x over previous
//
#include <hip/hip_runtime.h>

#define NN 10000
#define NE 160000
#define NE2 (NE + NN)
#define NG 64
#define EDIM 32

typedef _Float16 f16;
typedef __attribute__((ext_vector_type(2))) _Float16 f16x2;
typedef __attribute__((ext_vector_type(4))) _Float16 f16x4;
typedef __attribute__((ext_vector_type(8))) _Float16 f16x8;
typedef __attribute__((ext_vector_type(4))) float f32x4;
typedef __attribute__((ext_vector_type(8))) unsigned short u16x8;

__device__ __forceinline__ float lrelu(float x) { return fmaxf(x, 0.2f * x); }
__device__ __forceinline__ float elu1(float x) { return x > 0.f ? x : __expf(x) - 1.f; }

// ========== weight prep body ==========

template <int CIN, int C>
__device__ __forceinline__ void wprep_body(int b, int tid,
                                           const float* __restrict__ W,
                                           const float* __restrict__ We,
                                           const float* __restrict__ as_,
                                           const float* __restrict__ ad_,
                                           const float* __restrict__ ae_,
                                           f16* __restrict__ Bt,
                                           float* __restrict__ asd,
                                           float* __restrict__ Wf,
                                           float (*t)[33]) {
    constexpr int K4 = 4 * CIN;
    constexpr int KT = CIN / 32, CT = C / 32;
    constexpr int TB = 4 * KT * CT;
    constexpr int FB = CIN / 64;
    if (b < TB) {
        int h = b / (KT * CT);
        int rem = b % (KT * CT);
        int k0 = (rem / CT) * 32, c0 = (rem % CT) * 32;
        int i = tid >> 5, j = tid & 31;
#pragma unroll
        for (int it = 0; it < 4; ++it)
            t[i + it * 8][j] = W[(size_t)(k0 + i + it * 8) * (4 * C) + h * C + c0 + j];
        __syncthreads();
#pragma unroll
        for (int it = 0; it < 4; ++it) {
            int jj = (tid >> 5) + it * 8, ii = tid & 31;
            Bt[(size_t)(c0 + jj) * K4 + h * CIN + k0 + ii] = (f16)t[ii][jj];
        }
    } else if (b < TB + FB) {
        int k = (b - TB) * 64 + (tid >> 2), h = tid & 3;
        const float4* wr = (const float4*)(W + (size_t)k * (4 * C) + h * C);
        const float4* a4 = (const float4*)(as_ + h * C);
        const float4* d4 = (const float4*)(ad_ + h * C);
        float s = 0.f, d = 0.f;
        for (int c = 0; c < C / 4; ++c) {
            float4 w = wr[c], av = a4[c], dv = d4[c];
            s += w.x * av.x + w.y * av.y + w.z * av.z + w.w * av.w;
            d += w.x * dv.x + w.y * dv.y + w.z * dv.z + w.w * dv.w;
        }
        asd[h * CIN + k] = s;
        asd[4 * CIN + h * CIN + k] = d;
    } else if (tid < 128) {
        int dd = tid >> 2, h = tid & 3;
        const float4* wr = (const float4*)(We + (size_t)dd * (4 * C) + h * C);
        const float4* a4 = (const float4*)(ae_ + h * C);
        float s = 0.f;
        for (int c = 0; c < C / 4; ++c) {
            float4 w = wr[c], av = a4[c];
            s += w.x * av.x + w.y * av.y + w.z * av.z + w.w * av.w;
        }
        Wf[dd * 4 + h] = s;
    }
}

// ===== k_init: wprep(331) | deg atomics(625) | x cast(1250) | invc(1) =====

__global__ __launch_bounds__(256) void k_init(
    const float* W1, const float* We1, const float* as1, const float* ad1, const float* ae1,
    f16* Bt1, float* asd1, float* Wf1,
    const float* W2, const float* We2, const float* as2, const float* ad2, const float* ae2,
    f16* Bt2, float* asd2, float* Wf2,
    const float* W3, const float* We3, const float* as3, const float* ad3, const float* ae3,
    f16* Bt3, float* asd3, float* Wf3,
    const int* ei, int* deg, const float* x, f16* x16,
    const int* batch, float* invc) {
    __shared__ float t[32][33];
    int b = blockIdx.x, tid = threadIdx.x;
    if (b < 67) {
        wprep_body<128, 128>(b, tid, W1, We1, as1, ad1, ae1, Bt1, asd1, Wf1, t);
    } else if (b < 198) {
        wprep_body<128, 256>(b - 67, tid, W2, We2, as2, ad2, ae2, Bt2, asd2, Wf2, t);
    } else if (b < 331) {
        wprep_body<256, 128>(b - 198, tid, W3, We3, as3, ad3, ae3, Bt3, asd3, Wf3, t);
    } else if (b < 956) {
        int e = (b - 331) * 256 + tid;
        atomicAdd(&deg[ei[NE + e]], 1);
    } else if (b < 2206) {
        int i = (b - 956) * 256 + tid;
        float4 v = ((const float4*)x)[i];
        f16x4 o;
        o[0] = (f16)v.x; o[1] = (f16)v.y; o[2] = (f16)v.z; o[3] = (f16)v.w;
        *(f16x4*)(x16 + i * 4) = o;
    } else if (tid < NG) {
        int g = tid;
        int lo = 0, hi = NN;
        while (lo < hi) { int mid = (lo + hi) >> 1; if (batch[mid] < g) lo = mid + 1; else hi = mid; }
        int start = lo;
        lo = start; hi = NN;
        while (lo < hi) { int mid = (lo + hi) >> 1; if (batch[mid] < g + 1) lo = mid + 1; else hi = mid; }
        invc[g] = 1.f / fmaxf((float)(lo - start), 1.f);
    }
}

// ============== scan (row_ptr/cursor) ==============

__global__ __launch_bounds__(1024) void k_scan2(const int* __restrict__ deg,
                                                int* __restrict__ row_ptr,
                                                int* __restrict__ cursor) {
    int tid = threadIdx.x;
    int vals[10];
    int run = 0;
#pragma unroll
    for (int i = 0; i < 10; ++i) {
        int n = tid * 10 + i;
        int v = (n < NN) ? (deg[n] + 1) : 0;
        run += v;
        vals[i] = run;
    }
    int total = run;
    int lane = tid & 63, wid = tid >> 6;
    int sc = total;
#pragma unroll
    for (int off = 1; off < 64; off <<= 1) {
        int t = __shfl_up(sc, off);
        if (lane >= off) sc += t;
    }
    __shared__ int wsum[16];
    if (lane == 63) wsum[wid] = sc;
    __syncthreads();
    if (tid == 0) {
        int a = 0;
#pragma unroll
        for (int w = 0; w < 16; ++w) { int t = wsum[w]; wsum[w] = a; a += t; }
    }
    __syncthreads();
    int excl = sc - total + wsum[wid];
#pragma unroll
    for (int i = 0; i < 10; ++i) {
        int n = tid * 10 + i;
        if (n < NN) {
            int prev = i ? vals[i - 1] : 0;
            row_ptr[n + 1] = excl + vals[i];
            cursor[n] = excl + prev;
        }
    }
    if (tid == 0) row_ptr[0] = 0;
}

// ===== k_fill_e4: CSR fill + real-edge e4 (665 blocks) | layer-1 alnode (2500) =====

__global__ __launch_bounds__(256) void k_fill_e4(const int* __restrict__ ei,
                                                 int* __restrict__ cursor,
                                                 int* __restrict__ src_sorted,
                                                 int* __restrict__ dst_sorted,
                                                 int* __restrict__ selfpos,
                                                 const float* __restrict__ eattr,
                                                 const float* __restrict__ Wf1,
                                                 const float* __restrict__ Wf2,
                                                 const float* __restrict__ Wf3,
                                                 float* __restrict__ e4all,
                                                 const f16* __restrict__ x16,
                                                 const float* __restrict__ asd1,
                                                 float* __restrict__ als1,
                                                 float* __restrict__ ald1) {
    __shared__ float smem[1024];
    int b = blockIdx.x, tid = threadIdx.x;
    if (b < 665) {
        for (int i = tid; i < 384; i += 256)
            smem[i] = (i < 128) ? Wf1[i] : (i < 256) ? Wf2[i - 128] : Wf3[i - 256];
        __syncthreads();
        int e = b * 256 + tid;
        if (e >= NE2) return;
        if (e < NE) {
            int s = ei[e], d = ei[NE + e];
            int p = atomicAdd(&cursor[d], 1);
            src_sorted[p] = s;
            dst_sorted[p] = d;
            float4 v[8];
            const float4* er = (const float4*)(eattr + (size_t)e * EDIM);
#pragma unroll
            for (int i = 0; i < 8; ++i) v[i] = er[i];
#pragma unroll
            for (int l = 0; l < 3; ++l) {
                float a0 = 0.f, a1 = 0.f, a2 = 0.f, a3 = 0.f;
#pragma unroll
                for (int d4 = 0; d4 < 8; ++d4) {
                    const float* w = &smem[l * 128 + d4 * 16];
                    a0 += v[d4].x * w[0] + v[d4].y * w[4] + v[d4].z * w[8]  + v[d4].w * w[12];
                    a1 += v[d4].x * w[1] + v[d4].y * w[5] + v[d4].z * w[9]  + v[d4].w * w[13];
                    a2 += v[d4].x * w[2] + v[d4].y * w[6] + v[d4].z * w[10] + v[d4].w * w[14];
                    a3 += v[d4].x * w[3] + v[d4].y * w[7] + v[d4].z * w[11] + v[d4].w * w[15];
                }
                ((float4*)e4all)[(size_t)l * NE2 + p] = make_float4(a0, a1, a2, a3);
            }
        } else {
            int n = e - NE;
            int p = atomicAdd(&cursor[n], 1);
            src_sorted[p] = n;
            dst_sorted[p] = n;
            selfpos[n] = p;
        }
    } else {
        float* sA = smem;
        float* sD = smem + 512;
        for (int i = tid; i < 512; i += 256) { sA[i] = asd1[i]; sD[i] = asd1[512 + i]; }
        __syncthreads();
        int wid = tid >> 6, lane = tid & 63;
        int node = (b - 665) * 4 + wid;
        int h = lane >> 4, c16 = lane & 15;
        const f16* xr = x16 + (size_t)node * 128 + c16 * 8;
        f16x8 v = *(const f16x8*)xr;
        float s = 0.f, d = 0.f;
#pragma unroll
        for (int i = 0; i < 8; ++i) {
            float f = (float)v[i];
            s += f * sA[h * 128 + c16 * 8 + i];
            d += f * sD[h * 128 + c16 * 8 + i];
        }
#pragma unroll
        for (int off = 1; off < 16; off <<= 1) { s += __shfl_xor(s, off); d += __shfl_xor(d, off); }
        if (c16 == 0) { als1[node * 4 + h] = s; ald1[node * 4 + h] = d; }
    }
}

// ===== self-loop e4 = mean of real-edge e4 (linearity of scatter-mean) =====

__global__ __launch_bounds__(256) void k_e4self(const int* __restrict__ row_ptr,
                                                const int* __restrict__ selfpos,
                                                float* __restrict__ e4all) {
    int t = blockIdx.x * 256 + threadIdx.x;  // 625 blocks exact: NN*16 threads
    int node = t >> 4, sub = t & 15;
    if (sub >= 12) return;
    int l = sub >> 2, c = sub & 3;
    int beg = row_ptr[node], end = row_ptr[node + 1];
    int sp = selfpos[node];
    const float* base = e4all + (size_t)l * NE2 * 4 + c;
    float s = 0.f;
    for (int j = beg; j < end; ++j)
        if (j != sp) s += base[(size_t)j * 4];
    float inv = 1.f / fmaxf((float)(end - beg - 1), 1.f);
    e4all[(size_t)l * NE2 * 4 + (size_t)sp * 4 + c] = s * inv;
}

// ===== alnode: als[n,h] = h[n]·âs[h] (layers 2/3) =====

template <int CIN>
__global__ __launch_bounds__(256) void k_alnode2(const f16* __restrict__ xp,
                                                 const float* __restrict__ asd,
                                                 float* __restrict__ als,
                                                 float* __restrict__ ald) {
    __shared__ float sA[4 * CIN], sD[4 * CIN];
    for (int i = threadIdx.x; i < 4 * CIN; i += 256) { sA[i] = asd[i]; sD[i] = asd[4 * CIN + i]; }
    __syncthreads();
    int wid = threadIdx.x >> 6, lane = threadIdx.x & 63;
    int node = blockIdx.x * 4 + wid;
    int h = lane >> 4, c16 = lane & 15;
    constexpr int KC = CIN / 16;
    const f16* xr = xp + (size_t)node * CIN + c16 * KC;
    float s = 0.f, d = 0.f;
#pragma unroll
    for (int p = 0; p < KC / 8; ++p) {
        f16x8 v = *(const f16x8*)(xr + p * 8);
        const float* wa = &sA[h * CIN + c16 * KC + p * 8];
        const float* wd = &sD[h * CIN + c16 * KC + p * 8];
#pragma unroll
        for (int i = 0; i < 8; ++i) {
            float f = (float)v[i];
            s += f * wa[i];
            d += f * wd[i];
        }
    }
#pragma unroll
    for (int off = 1; off < 16; off <<= 1) { s += __shfl_xor(s, off); d += __shfl_xor(d, off); }
    if (c16 == 0) { als[node * 4 + h] = s; ald[node * 4 + h] = d; }
}

// ===== edge-parallel numerator pass: t = exp(lrelu(e4 + als[src] + ald[dst])) =====

__global__ __launch_bounds__(256) void k_t(const float* __restrict__ e4,
                                           const int* __restrict__ src_sorted,
                                           const int* __restrict__ dst_sorted,
                                           const float* __restrict__ als,
                                           const float* __restrict__ ald,
                                           float* __restrict__ tbuf) {
    int j = blockIdx.x * 256 + threadIdx.x;
    if (j >= NE2) return;
    float4 ev = ((const float4*)e4)[j];
    int src = src_sorted[j], dst = dst_sorted[j];
    float4 sv = ((const float4*)als)[src];
    float4 dv = ((const float4*)ald)[dst];
    float4 t;
    t.x = __expf(lrelu(ev.x + sv.x + dv.x));
    t.y = __expf(lrelu(ev.y + sv.y + dv.y));
    t.z = __expf(lrelu(ev.z + sv.z + dv.z));
    t.w = __expf(lrelu(ev.w + sv.w + dv.w));
    ((float4*)tbuf)[j] = t;
}

// ===== lean aggregation: gather + weighted sum only; edge-split across 2 waves =====
// WPN = 2*CSPLIT waves/node: CSPLIT col-halves x 2 edge-parities, LDS pairwise combine.

template <int CIN, int CSPLIT>
__global__ __launch_bounds__(256) void k_agg3(const int* __restrict__ row_ptr,
                                              const int* __restrict__ src_sorted,
                                              const float* __restrict__ tbuf,
                                              const f16* __restrict__ xp,
                                              f16* __restrict__ aggcat) {
    constexpr int CHUNK = CIN / CSPLIT;   // cols per wave (=128)
    constexpr int EPL = CHUNK / 64;       // =2 halfs per lane
    constexpr int WPN = 2 * CSPLIT;
    constexpr int NPB = 4 / WPN;
    int wid = threadIdx.x >> 6, lane = threadIdx.x & 63;
    int node = blockIdx.x * NPB + wid / WPN;
    int sub = wid % WPN;
    int ch = sub >> 1;                    // col half
    int ep = sub & 1;                     // edge parity
    int pair = wid >> 1;                  // combine-pair id in block (0..1)
    int beg = row_ptr[node], end = row_ptr[node + 1];
    const float4* t4 = (const float4*)tbuf;
    float s0 = 0.f, s1 = 0.f, s2 = 0.f, s3 = 0.f;
    float a0[EPL] = {}, a1[EPL] = {}, a2[EPL] = {}, a3[EPL] = {};
    const f16* xbase = xp + ch * CHUNK + lane * EPL;
#pragma unroll 4
    for (int j = beg + ep; j < end; j += 2) {
        float4 t = t4[j];
        int src = src_sorted[j];
        s0 += t.x; s1 += t.y; s2 += t.z; s3 += t.w;
        f16x2 v = *(const f16x2*)(xbase + (size_t)src * CIN);
        float f0 = (float)v[0], f1 = (float)v[1];
        a0[0] += t.x * f0; a0[1] += t.x * f1;
        a1[0] += t.y * f0; a1[1] += t.y * f1;
        a2[0] += t.z * f0; a2[1] += t.z * f1;
        a3[0] += t.w * f0; a3[1] += t.w * f1;
    }
    __shared__ float lacc[2][64][8];
    __shared__ float ls[2][4];
    if (ep == 0) {
        float* p = &lacc[pair][lane][0];
        p[0] = a0[0]; p[1] = a0[1]; p[2] = a1[0]; p[3] = a1[1];
        p[4] = a2[0]; p[5] = a2[1]; p[6] = a3[0]; p[7] = a3[1];
        if (lane == 0) { ls[pair][0] = s0; ls[pair][1] = s1; ls[pair][2] = s2; ls[pair][3] = s3; }
    }
    __syncthreads();
    if (ep == 1) {
        const float* p = &lacc[pair][lane][0];
        a0[0] += p[0]; a0[1] += p[1]; a1[0] += p[2]; a1[1] += p[3];
        a2[0] += p[4]; a2[1] += p[5]; a3[0] += p[6]; a3[1] += p[7];
        s0 += ls[pair][0]; s1 += ls[pair][1]; s2 += ls[pair][2]; s3 += ls[pair][3];
        float i0 = 1.f / (s0 + 1e-16f), i1 = 1.f / (s1 + 1e-16f);
        float i2 = 1.f / (s2 + 1e-16f), i3 = 1.f / (s3 + 1e-16f);
        f16* ob = aggcat + (size_t)node * 4 * CIN + ch * CHUNK + lane * EPL;
        f16x2 o;
        o[0] = (f16)(a0[0] * i0); o[1] = (f16)(a0[1] * i0); *(f16x2*)(ob + 0 * CIN) = o;
        o[0] = (f16)(a1[0] * i1); o[1] = (f16)(a1[1] * i1); *(f16x2*)(ob + 1 * CIN) = o;
        o[0] = (f16)(a2[0] * i2); o[1] = (f16)(a2[1] * i2); *(f16x2*)(ob + 2 * CIN) = o;
        o[0] = (f16)(a3[0] * i3); o[1] = (f16)(a3[1] * i3); *(f16x2*)(ob + 3 * CIN) = o;
    }
}

// ===== MFMA GEMM, BM=32 BN=64, double-buffered reg-staged LDS, XOR swizzle =====
// hout = elu(0.25*A@Bt^T + b) [fp16]; POOL: LDS group-window mean-pool into out.

template <int K4, int C, bool POOL>
__global__ __launch_bounds__(256) void k_gemm2(const f16* __restrict__ A,
                                               const f16* __restrict__ Bt,
                                               const float* __restrict__ bias,
                                               f16* __restrict__ hout,
                                               const int* __restrict__ batch,
                                               const float* __restrict__ invc,
                                               float* __restrict__ out) {
    constexpr int NS = K4 / 32;
    __shared__ f16 Als[2][32 * 32];
    __shared__ f16 Bls[2][64 * 32];
    __shared__ float pacc[4][64];     // POOL: group-window accumulators
    int bm = blockIdx.x * 32, bn = blockIdx.y * 64;
    int tid = threadIdx.x;
    int wid = tid >> 6, lane = tid & 63;
    int mq = wid >> 1, nq = wid & 1;
    int fr = lane & 15, kc = lane >> 4;

    if (POOL) pacc[tid >> 6][tid & 63] = 0.f;

    int ar = tid >> 2, ac = tid & 3;                     // stage coords
    const f16* Ap = A + (size_t)(bm + (ar & 31)) * K4 + ac * 8;
    const f16* Bp = Bt + (size_t)(bn + ar) * K4 + ac * 8;
    bool aok = (tid < 128) && (bm + ar < NN);
    int wA = (ar & 31) * 32 + ((ac ^ (ar & 3)) * 8);     // swizzled write offsets
    int wB = ar * 32 + ((ac ^ (ar & 3)) * 8);
    int kx = (kc ^ (fr & 3)) * 8;                        // swizzled read k-offset
    int rA = (mq * 16 + fr) * 32 + kx;
    int rB0 = (nq * 32 + fr) * 32 + kx;
    int rB1 = rB0 + 16 * 32;

    f32x4 acc0 = (f32x4){0.f, 0.f, 0.f, 0.f};
    f32x4 acc1 = (f32x4){0.f, 0.f, 0.f, 0.f};

    u16x8 va = (u16x8)0, vb;
    if (aok) va = *(const u16x8*)Ap;
    vb = *(const u16x8*)Bp;
    if (tid < 128) *(u16x8*)&Als[0][wA] = va;
    *(u16x8*)&Bls[0][wB] = vb;
    __syncthreads();

#pragma unroll
    for (int s = 0; s < NS; ++s) {
        int cur = s & 1;
        if (s + 1 < NS) {
            va = (u16x8)0;
            if (aok) va = *(const u16x8*)(Ap + (s + 1) * 32);
            vb = *(const u16x8*)(Bp + (s + 1) * 32);
        }
        f16x8 af  = *(const f16x8*)&Als[cur][rA];
        f16x8 bf0 = *(const f16x8*)&Bls[cur][rB0];
        f16x8 bf1 = *(const f16x8*)&Bls[cur][rB1];
        acc0 = __builtin_amdgcn_mfma_f32_16x16x32_f16(af, bf0, acc0, 0, 0, 0);
        acc1 = __builtin_amdgcn_mfma_f32_16x16x32_f16(af, bf1, acc1, 0, 0, 0);
        if (s + 1 < NS) {
            if (tid < 128) *(u16x8*)&Als[cur ^ 1][wA] = va;
            *(u16x8*)&Bls[cur ^ 1][wB] = vb;
        }
        __syncthreads();
    }

    int cr = kc * 4, cc = fr;
    int lc0 = nq * 32 + cc, lc1 = lc0 + 16;              // local cols in [0,64)
    int col0 = bn + lc0, col1 = bn + lc1;
    float b0 = bias[col0], b1 = bias[col1];
    int g0 = POOL ? batch[bm] : 0;
#pragma unroll
    for (int r = 0; r < 4; ++r) {
        int row = bm + mq * 16 + cr + r;
        if (row >= NN) continue;
        float v0 = elu1(0.25f * acc0[r] + b0);
        float v1 = elu1(0.25f * acc1[r] + b1);
        if (POOL) {
            int g = batch[row];
            float ic = invc[g];
            int wi = g - g0;
            if (wi < 4) {
                atomicAdd(&pacc[wi][lc0], v0 * ic);
                atomicAdd(&pacc[wi][lc1], v1 * ic);
            } else {  // rare fallback: tile spans >4 groups
                atomicAdd(&out[(size_t)g * C + col0], v0 * ic);
                atomicAdd(&out[(size_t)g * C + col1], v1 * ic);
            }
        } else {
            f16* cp = hout + (size_t)row * C + col0;
            cp[0] = (f16)v0;
            cp[16] = (f16)v1;
        }
    }
    if (POOL) {
        __syncthreads();
        int wi = tid >> 6, c = tid & 63;
        float val = pacc[wi][c];
        int g = g0 + wi;
        if (val != 0.f && g < NG)
            atomicAdd(&out[(size_t)g * C + bn + c], val);
    }
}

// ============================ host side ============================

struct Ws {
    f16 *x16, *hA, *hB, *aggcat, *Wt1, *Wt2, *Wt3;
    float *als1, *ald1, *als2, *ald2, *als3, *ald3;
    float *e4all, *tbuf, *asd1, *asd2, *asd3, *Wf1, *Wf2, *Wf3, *invc;
    int *deg, *row_ptr, *cursor, *src_sorted, *dst_sorted, *selfpos;
};

static void carve(void* base, Ws& w) {
    char* p = (char*)base;
    size_t off = 0;
    auto take = [&](size_t bytes) {
        off = (off + 255) & ~(size_t)255;
        void* r = p + off;
        off += bytes;
        return r;
    };
    w.x16        = (f16*)take((size_t)NN * 128 * 2);
    w.hA         = (f16*)take((size_t)NN * 128 * 2);
    w.hB         = (f16*)take((size_t)NN * 256 * 2);
    w.aggcat     = (f16*)take((size_t)NN * 1024 * 2);
    w.Wt1        = (f16*)take((size_t)512 * 128 * 2);
    w.Wt2        = (f16*)take((size_t)512 * 256 * 2);
    w.Wt3        = (f16*)take((size_t)1024 * 128 * 2);
    w.als1       = (float*)take((size_t)NN * 4 * 4);
    w.ald1       = (float*)take((size_t)NN * 4 * 4);
    w.als2       = (float*)take((size_t)NN * 4 * 4);
    w.ald2       = (float*)take((size_t)NN * 4 * 4);
    w.als3       = (float*)take((size_t)NN * 4 * 4);
    w.ald3       = (float*)take((size_t)NN * 4 * 4);
    w.e4all      = (float*)take((size_t)3 * NE2 * 4 * 4);
    w.tbuf       = (float*)take((size_t)NE2 * 4 * 4);
    w.asd1       = (float*)take(2 * 4 * 128 * 4);
    w.asd2       = (float*)take(2 * 4 * 128 * 4);
    w.asd3       = (float*)take(2 * 4 * 256 * 4);
    w.Wf1        = (float*)take(128 * 4);
    w.Wf2        = (float*)take(128 * 4);
    w.Wf3        = (float*)take(128 * 4);
    w.invc       = (float*)take(NG * 4);
    w.deg        = (int*)take((size_t)NN * 4);
    w.row_ptr    = (int*)take((size_t)(NN + 1) * 4);
    w.cursor     = (int*)take((size_t)NN * 4);
    w.src_sorted = (int*)take((size_t)NE2 * 4);
    w.dst_sorted = (int*)take((size_t)NE2 * 4);
    w.selfpos    = (int*)take((size_t)NN * 4);
}

extern "C" void kernel_launch(void* const* d_in, const int* in_sizes, int n_in,
                              void* d_out, int out_size, void* d_ws, size_t ws_size,
                              hipStream_t stream) {
    const float* x     = (const float*)d_in[0];
    const int*   ei    = (const int*)d_in[1];
    const float* eattr = (const float*)d_in[2];
    const int*   batch = (const int*)d_in[3];
    const float* W[3]  = {(const float*)d_in[4],  (const float*)d_in[10], (const float*)d_in[16]};
    const float* We[3] = {(const float*)d_in[5],  (const float*)d_in[11], (const float*)d_in[17]};
    const float* as_[3]= {(const float*)d_in[6],  (const float*)d_in[12], (const float*)d_in[18]};
    const float* ad_[3]= {(const float*)d_in[7],  (const float*)d_in[13], (const float*)d_in[19]};
    const float* ae_[3]= {(const float*)d_in[8],  (const float*)d_in[14], (const float*)d_in[20]};
    const float* b_[3] = {(const float*)d_in[9],  (const float*)d_in[15], (const float*)d_in[21]};
    float* out = (float*)d_out;

    Ws w;
    carve(d_ws, w);

    hipMemsetAsync(w.deg, 0, (size_t)NN * 4, stream);
    hipMemsetAsync(out, 0, (size_t)NG * 128 * 4, stream);

    // ---- init: weight prep + deg + x cast + group inv-counts ----
    k_init<<<2207, 256, 0, stream>>>(
        W[0], We[0], as_[0], ad_[0], ae_[0], w.Wt1, w.asd1, w.Wf1,
        W[1], We[1], as_[1], ad_[1], ae_[1], w.Wt2, w.asd2, w.Wf2,
        W[2], We[2], as_[2], ad_[2], ae_[2], w.Wt3, w.asd3, w.Wf3,
        ei, w.deg, x, w.x16, batch, w.invc);

    k_scan2<<<1, 1024, 0, stream>>>(w.deg, w.row_ptr, w.cursor);

    // ---- CSR fill + real-edge e4 + layer-1 alnode; then self-loop e4 ----
    k_fill_e4<<<3165, 256, 0, stream>>>(ei, w.cursor, w.src_sorted, w.dst_sorted,
                                        w.selfpos, eattr, w.Wf1, w.Wf2, w.Wf3, w.e4all,
                                        w.x16, w.asd1, w.als1, w.ald1);
    k_e4self<<<625, 256, 0, stream>>>(w.row_ptr, w.selfpos, w.e4all);

    const float* e4_1 = w.e4all;
    const float* e4_2 = w.e4all + (size_t)NE2 * 4;
    const float* e4_3 = w.e4all + (size_t)2 * NE2 * 4;

    // ---- layer 1 ----
    k_t<<<665, 256, 0, stream>>>(e4_1, w.src_sorted, w.dst_sorted, w.als1, w.ald1, w.tbuf);
    k_agg3<128, 1><<<NN / 2, 256, 0, stream>>>(w.row_ptr, w.src_sorted, w.tbuf,
                                               w.x16, w.aggcat);
    k_gemm2<512, 128, false><<<dim3(313, 2), 256, 0, stream>>>(w.aggcat, w.Wt1, b_[0],
                                                               w.hA, nullptr, nullptr, nullptr);
    // ---- layer 2 ----
    k_alnode2<128><<<NN / 4, 256, 0, stream>>>(w.hA, w.asd2, w.als2, w.ald2);
    k_t<<<665, 256, 0, stream>>>(e4_2, w.src_sorted, w.dst_sorted, w.als2, w.ald2, w.tbuf);
    k_agg3<128, 1><<<NN / 2, 256, 0, stream>>>(w.row_ptr, w.src_sorted, w.tbuf,
                                               w.hA, w.aggcat);
    k_gemm2<512, 256, false><<<dim3(313, 4), 256, 0, stream>>>(w.aggcat, w.Wt2, b_[1],
                                                               w.hB, nullptr, nullptr, nullptr);
    // ---- layer 3 + fused mean-pool ----
    k_alnode2<256><<<NN / 4, 256, 0, stream>>>(w.hB, w.asd3, w.als3, w.ald3);
    k_t<<<665, 256, 0, stream>>>(e4_3, w.src_sorted, w.dst_sorted, w.als3, w.ald3, w.tbuf);
    k_agg3<256, 2><<<NN, 256, 0, stream>>>(w.row_ptr, w.src_sorted, w.tbuf,
                                           w.hB, w.aggcat);
    k_gemm2<1024, 128, true><<<dim3(313, 2), 256, 0, stream>>>(w.aggcat, w.Wt3, b_[2],
                                                               nullptr, batch, w.invc, out);
}